// Round 17
// baseline (937.116 us; speedup 1.0000x reference)
//
#include <hip/hip_runtime.h>
#include <cstdint>
#include <cstddef>

typedef unsigned short u16;
typedef __bf16 bf16x8 __attribute__((ext_vector_type(8)));
typedef float f32x4 __attribute__((ext_vector_type(4)));
typedef unsigned short u16x8 __attribute__((ext_vector_type(8)));
typedef unsigned short u16x4 __attribute__((ext_vector_type(4)));

__device__ __forceinline__ u16 f2bf(float f) {
  union { float f; unsigned u; } x; x.f = f;
  unsigned r = x.u + 0x7fffu + ((x.u >> 16) & 1u);   // RNE
  return (u16)(r >> 16);
}
__device__ __forceinline__ float bf2f(u16 u) {
  union { unsigned u; float f; } x; x.u = ((unsigned)u) << 16;
  return x.f;
}
// async global->LDS, 16B/lane; LDS dest = wave-uniform base + lane*16 (linear)
__device__ __forceinline__ void gload16(const void* g, void* l) {
  __builtin_amdgcn_global_load_lds(
      (const __attribute__((address_space(1))) unsigned int*)g,
      (__attribute__((address_space(3))) unsigned int*)l, 16, 0, 0);
}

// ---------------------------------------------------------------------------
// GEMM: C = A[.][K](lda) @ Bt^T + bias. Bt[N][K] bf16. 128x128 tile, BK=32,
// 4 waves, 2-phase double-buffered (prefetch before compute, one barrier per
// K-step). Slot swizzle slot^(row&3) both sides. 1-D grid, col-fastest +
// bijective XCD chunking (nwg%8==0).
// AF32=0: A bf16, global_load_lds staging.
// AF32=1: A fp32, T14 split staging: f32 loads issued BEFORE compute,
//         convert + swizzled ds_write AFTER compute (hides HBM latency).
// MODE 0: natural bf16 out C0[r*ldc + coff + c];  MODE 1: + ReLU
// MODE 2: split route: col<vsplit natural into C0 (+coff);
//         col>=vsplit window-transposed into C2[win][c-vsplit][tok&31]
// MODE 3: pure window-transposed into C2[win][c][tok&31]
// ---------------------------------------------------------------------------
template<int MODE, int AF32>
__global__ __launch_bounds__(256) void gemm_bt(
    const void* __restrict__ Ap_, int lda, const u16* __restrict__ Bt,
    const float* __restrict__ bias, u16* __restrict__ C0, int ldc, int coff,
    u16* __restrict__ C2, int vsplit, int N, int K, int gy)
{
  __shared__ u16 As[2][128 * 32];
  __shared__ u16 Bs[2][128 * 32];
  const int tid  = threadIdx.x;
  const int lane = tid & 63, w = tid >> 6;
  const int nwg = gridDim.x, o = blockIdx.x;
  const int lid = (o & 7) * (nwg >> 3) + (o >> 3);   // contiguous lid -> same XCD
  const int by = lid % gy, bx = lid / gy;
  const int row0 = bx * 128, col0 = by * 128;
  const int wr = (w >> 1) * 64, wc = (w & 1) * 64;
  const int fr = lane & 15, fg = lane >> 4;          // fragment row / k-group
  const int srow  = (w << 5) + (lane >> 2);
  const int sslot = (lane & 3) ^ ((lane >> 2) & 3);
  const u16*   Ab = (const u16*)Ap_;
  const float* Af = (const float*)Ap_;

  auto stageB = [&](int buf, int k0) {
    #pragma unroll
    for (int h = 0; h < 2; ++h)
      gload16((const char*)Bt + ((size_t)(col0 + srow + h*16) * K + k0) * 2 + sslot*16,
              &Bs[buf][((w << 5) + h*16) * 32]);
  };
  auto stageA16 = [&](int buf, int k0) {
    #pragma unroll
    for (int h = 0; h < 2; ++h)
      gload16((const char*)Ab + ((size_t)(row0 + srow + h*16) * lda + k0) * 2 + sslot*16,
              &As[buf][((w << 5) + h*16) * 32]);
  };
  // fp32 A: 512 slots (128 rows x 4 slots of 8 values); 2 slots/thread
  f32x4 pre[2][2];
  auto loadA32 = [&](int k0) {
    #pragma unroll
    for (int p = 0; p < 2; ++p) {
      const int sidx = tid + p*256, rr = sidx >> 2, sl = sidx & 3;
      const float* src = &Af[(size_t)(row0 + rr) * lda + k0 + sl*8];
      pre[p][0] = *(const f32x4*)src;
      pre[p][1] = *(const f32x4*)(src + 4);
    }
  };
  auto writeA32 = [&](int buf) {
    #pragma unroll
    for (int p = 0; p < 2; ++p) {
      const int sidx = tid + p*256, rr = sidx >> 2, sl = sidx & 3;
      u16x8 o = { f2bf(pre[p][0][0]), f2bf(pre[p][0][1]),
                  f2bf(pre[p][0][2]), f2bf(pre[p][0][3]),
                  f2bf(pre[p][1][0]), f2bf(pre[p][1][1]),
                  f2bf(pre[p][1][2]), f2bf(pre[p][1][3]) };
      *(u16x8*)&As[buf][rr*32 + ((sl ^ (rr & 3)) << 3)] = o;
    }
  };

  f32x4 acc[4][4] = {};

  if (AF32) { loadA32(0); stageB(0, 0); writeA32(0); }
  else      { stageA16(0, 0); stageB(0, 0); }
  __syncthreads();                  // prologue drain (vm + lgkm)
  int cur = 0;
  for (int k0 = 0; k0 < K; k0 += 32) {
    const int has_next = (k0 + 32 < K);
    if (has_next) {                 // issue next-tile loads before compute
      if (AF32) loadA32(k0 + 32);
      else      stageA16(cur ^ 1, k0 + 32);
      stageB(cur ^ 1, k0 + 32);
    }
    bf16x8 af[4], bf[4];
    #pragma unroll
    for (int i = 0; i < 4; ++i) {
      const int r = wr + i*16 + fr;
      af[i] = *(const bf16x8*)&As[cur][r*32 + ((fg ^ (fr & 3)) << 3)];
    }
    #pragma unroll
    for (int j = 0; j < 4; ++j) {
      const int r = wc + j*16 + fr;
      bf[j] = *(const bf16x8*)&Bs[cur][r*32 + ((fg ^ (fr & 3)) << 3)];
    }
    #pragma unroll
    for (int i = 0; i < 4; ++i)
      #pragma unroll
      for (int j = 0; j < 4; ++j)
        acc[i][j] = __builtin_amdgcn_mfma_f32_16x16x32_bf16(af[i], bf[j], acc[i][j], 0, 0, 0);
    if (AF32 && has_next) writeA32(cur ^ 1);   // T14: write-late
    __syncthreads();                // all reads done + next stage drained
    cur ^= 1;
  }

  // epilogue: D[row=fg*4+t][col=fr] per 16x16 fragment (m89-verified mapping)
  const int vpart = (MODE == 3) || (MODE == 2 && col0 >= vsplit);  // wave-uniform
  #pragma unroll
  for (int j = 0; j < 4; ++j) {
    const int c  = col0 + wc + j*16 + fr;
    const float bv = bias[c];
    #pragma unroll
    for (int i = 0; i < 4; ++i) {
      if (vpart) {
        const int cv = (MODE == 2) ? c - vsplit : c;
        const int rb = row0 + wr + i*16 + fg*4;   // 4 consecutive tokens
        u16x4 vv;
        #pragma unroll
        for (int t = 0; t < 4; ++t) vv[t] = f2bf(acc[i][j][t] + bv);
        *(u16x4*)&C2[((size_t)(rb >> 5) * 256 + cv) * 32 + (rb & 31)] = vv;
      } else {
        #pragma unroll
        for (int t = 0; t < 4; ++t) {
          const int r = row0 + wr + i*16 + fg*4 + t;
          float v = acc[i][j][t] + bv;
          if (MODE == 1) v = v > 0.f ? v : 0.f;
          C0[(size_t)r * ldc + coff + c] = f2bf(v);
        }
      }
    }
  }
}

// ---------------------------------------------------------------------------
// O-proj + bias + residual + LayerNorm fused (full-row tile).
// 128 rows x 256 cols per block, 8 waves (2 row x 4 col of 64x64), BK=32.
// RES_F32: residual read as fp32 (layer 1: raw query) or bf16 (layer 2).
// ---------------------------------------------------------------------------
template<int RES_F32>
__global__ __launch_bounds__(512) void gemm_oln(
    const u16* __restrict__ Ap, int lda, const u16* __restrict__ Bt,
    const float* __restrict__ bias, const void* __restrict__ Res,
    const float* __restrict__ g, const float* __restrict__ be,
    u16* __restrict__ Y, int K)
{
  __shared__ u16 As[2][128 * 32];    // 8 KB x2
  __shared__ u16 Bs[2][256 * 32];    // 16 KB x2
  __shared__ float2 red[128][4];     // 4 KB
  __shared__ float2 stats[128];      // 1 KB
  const int tid  = threadIdx.x;
  const int lane = tid & 63, w = tid >> 6;
  const int nwg = gridDim.x, o = blockIdx.x;
  const int lid = (o & 7) * (nwg >> 3) + (o >> 3);   // XCD chunk
  const int row0 = lid * 128;
  const int wr = (w >> 2) * 64, wc = (w & 3) * 64;
  const int fr = lane & 15, fg = lane >> 4;
  const int sr   = lane >> 2;
  const int sslot = (lane & 3) ^ ((lane >> 2) & 3);

  auto stage = [&](int buf, int k0) {
    gload16((const char*)Ap + ((size_t)(row0 + (w << 4) + sr) * lda + k0) * 2 + sslot*16,
            &As[buf][((w << 4)) * 32]);
    #pragma unroll
    for (int h = 0; h < 2; ++h)
      gload16((const char*)Bt + ((size_t)((w << 5) + h*16 + sr) * K + k0) * 2 + sslot*16,
              &Bs[buf][((w << 5) + h*16) * 32]);
  };

  f32x4 acc[4][4] = {};

  stage(0, 0);
  __syncthreads();
  int cur = 0;
  for (int k0 = 0; k0 < K; k0 += 32) {
    if (k0 + 32 < K) stage(cur ^ 1, k0 + 32);
    bf16x8 af[4], bf[4];
    #pragma unroll
    for (int i = 0; i < 4; ++i) {
      const int r = wr + i*16 + fr;
      af[i] = *(const bf16x8*)&As[cur][r*32 + ((fg ^ (fr & 3)) << 3)];
    }
    #pragma unroll
    for (int j = 0; j < 4; ++j) {
      const int r = wc + j*16 + fr;
      bf[j] = *(const bf16x8*)&Bs[cur][r*32 + ((fg ^ (fr & 3)) << 3)];
    }
    #pragma unroll
    for (int i = 0; i < 4; ++i)
      #pragma unroll
      for (int j = 0; j < 4; ++j)
        acc[i][j] = __builtin_amdgcn_mfma_f32_16x16x32_bf16(af[i], bf[j], acc[i][j], 0, 0, 0);
    __syncthreads();
    cur ^= 1;
  }

  // epilogue: v = acc + bias + residual; row stats; LN; store
  float ps[4][4] = {}, pq[4][4] = {};
  #pragma unroll
  for (int j = 0; j < 4; ++j) {
    const int c = wc + j*16 + fr;
    const float bv = bias[c];
    #pragma unroll
    for (int i = 0; i < 4; ++i) {
      #pragma unroll
      for (int t = 0; t < 4; ++t) {
        const int r = row0 + wr + i*16 + fg*4 + t;
        const float rv = RES_F32 ? ((const float*)Res)[(size_t)r * 256 + c]
                                 : bf2f(((const u16*)Res)[(size_t)r * 256 + c]);
        float v = acc[i][j][t] + bv + rv;
        acc[i][j][t] = v;
        ps[i][t] += v;
        pq[i][t] += v * v;
      }
    }
  }
  #pragma unroll
  for (int d = 1; d < 16; d <<= 1) {
    #pragma unroll
    for (int i = 0; i < 4; ++i)
      #pragma unroll
      for (int t = 0; t < 4; ++t) {
        ps[i][t] += __shfl_xor(ps[i][t], d, 64);
        pq[i][t] += __shfl_xor(pq[i][t], d, 64);
      }
  }
  if (fr == 0) {
    #pragma unroll
    for (int i = 0; i < 4; ++i)
      #pragma unroll
      for (int t = 0; t < 4; ++t)
        red[wr + i*16 + fg*4 + t][w & 3] = make_float2(ps[i][t], pq[i][t]);
  }
  __syncthreads();
  if (tid < 128) {
    float S = 0.f, Q = 0.f;
    #pragma unroll
    for (int ww = 0; ww < 4; ++ww) { float2 p = red[tid][ww]; S += p.x; Q += p.y; }
    const float m = S * (1.f/256.f);
    const float var = Q * (1.f/256.f) - m*m;
    stats[tid] = make_float2(m, rsqrtf(var + 1e-5f));
  }
  __syncthreads();
  #pragma unroll
  for (int i = 0; i < 4; ++i) {
    #pragma unroll
    for (int t = 0; t < 4; ++t) {
      const int rl = wr + i*16 + fg*4 + t;
      const float2 st = stats[rl];
      const size_t r = row0 + rl;
      #pragma unroll
      for (int j = 0; j < 4; ++j) {
        const int c = wc + j*16 + fr;
        Y[r * 256 + c] = f2bf((acc[i][j][t] - st.x) * st.y * g[c] + be[c]);
      }
    }
  }
}

// ---------------------------------------------------------------------------
// Fused FFN v5: Y = LayerNorm( X + relu(X@W1 + bf1)@W2 + bf2 ; g,be ).
// Lag-1 pipeline (T15/T3): iteration t runs GEMM1(t) and GEMM2(t-1).
// H double-buffered in wave-private LDS (Hs[t&1]) -> NO in-loop lgkmcnt:
// GEMM2(t-1) reads H written one iteration ago (same-wave in-order DS).
// T4 counted vmcnt: W1s 3 bufs / W2s 4 bufs, depth-2 prefetch, barrier at
// TOP of iteration (protects lag-1 restage of W2s[(t+2)&3] == (t-2)&3).
// T5 setprio(1) around the dual MFMA streams (role-diverse per m218b).
// LDS: 48K W1s + 64K W2s + 32K Hs + 4K b1s = 148 KB (1 block/CU).
// ---------------------------------------------------------------------------
template<int OUT_F32>
__global__ __launch_bounds__(512, 2) void ffn_fused(
    const u16* __restrict__ X, const u16* __restrict__ W1T,
    const float* __restrict__ b1, const u16* __restrict__ W2T,
    const float* __restrict__ b2, const float* __restrict__ g,
    const float* __restrict__ be, void* __restrict__ Y)
{
  __shared__ u16 W1s[3][32 * 256];   // [h 32][k 256], granule ^= row&7
  __shared__ u16 W2s[4][256 * 32];   // [n 256][k 32], granule ^= (row>>1)&3
  __shared__ u16 Hs[2][8][32 * 32];  // dbuf x per-wave [tok 32][h 32]
  __shared__ float b1s[1024];
  const int tid = threadIdx.x, lane = tid & 63, w = tid >> 6;
  const int fr = lane & 15, fg = lane >> 4;
  const int row0 = blockIdx.x * 256 + w * 32;
  const int hxor = (fr >> 1) & 3;

  auto stage = [&](int t) {
    const int b1f = t % 3, b2f = t & 3;
    #pragma unroll
    for (int h = 0; h < 2; ++h) {   // W1 slice [32][256]: 2 rows/wave/issue
      const int r = w*4 + h*2 + (lane >> 5);
      const int sl = (lane & 31) ^ (r & 7);
      gload16((const char*)W1T + ((size_t)((t << 5) + r) * 256 + sl*8) * 2,
              &W1s[b1f][(w*4 + h*2) * 256]);
    }
    #pragma unroll
    for (int h = 0; h < 2; ++h) {   // W2 slice [256][32]: 16 rows/wave/issue
      const int r = w*32 + h*16 + (lane >> 2);
      const int sl = (lane & 3) ^ ((r >> 1) & 3);
      gload16((const char*)W2T + ((size_t)r * 1024 + (t << 5) + sl*8) * 2,
              &W2s[b2f][(w*32 + h*16) * 32]);
    }
  };

  if (tid < 256) {
    f32x4 bv = *(const f32x4*)&b1[tid * 4];
    *(f32x4*)&b1s[tid * 4] = bv;
  }
  bf16x8 af[2][8];
  #pragma unroll
  for (int g2 = 0; g2 < 2; ++g2)
    #pragma unroll
    for (int kf = 0; kf < 8; ++kf)
      af[g2][kf] = *(const bf16x8*)&X[(size_t)(row0 + g2*16 + fr) * 256 + kf*32 + fg*8];
  asm volatile("s_waitcnt vmcnt(0) lgkmcnt(0)" ::: "memory");   // af + b1s drained

  f32x4 acc2[2][16] = {};   // out rows g*16+fg*4+t, col nf*16+fr

  auto gemm1 = [&](int t) {
    const int cur = t % 3;
    u16* Hw = &Hs[t & 1][w][0];
    f32x4 acc1[2][2] = {};   // [hf][g]
    #pragma unroll
    for (int kf = 0; kf < 8; ++kf) {
      #pragma unroll
      for (int hf = 0; hf < 2; ++hf) {
        const int n = hf*16 + fr;
        bf16x8 w1f = *(const bf16x8*)&W1s[cur][n*256 + ((((kf << 2) | fg) ^ (n & 7)) << 3)];
        acc1[hf][0] = __builtin_amdgcn_mfma_f32_16x16x32_bf16(w1f, af[0][kf], acc1[hf][0], 0, 0, 0);
        acc1[hf][1] = __builtin_amdgcn_mfma_f32_16x16x32_bf16(w1f, af[1][kf], acc1[hf][1], 0, 0, 0);
      }
    }
    #pragma unroll
    for (int g2 = 0; g2 < 2; ++g2) {
      #pragma unroll
      for (int hf = 0; hf < 2; ++hf) {
        const int h0 = hf*16 + fg*4;
        f32x4 b4 = *(const f32x4*)&b1s[(t << 5) + h0];
        u16x4 hv;
        #pragma unroll
        for (int tt = 0; tt < 4; ++tt) {
          float v = acc1[hf][g2][tt] + b4[tt];
          hv[tt] = f2bf(v > 0.f ? v : 0.f);
        }
        const int tok = g2*16 + fr;
        *(u16x4*)((char*)Hw + tok*64 + ((((hf << 1) | (fg >> 1)) ^ hxor) << 4)
                                     + ((fg & 1) << 3)) = hv;
      }
    }
  };
  auto gemm2 = [&](int t) {     // reads H written >=1 iteration ago
    const int cur = t & 3;
    const u16* Hw = &Hs[t & 1][w][0];
    bf16x8 hf2[2];
    #pragma unroll
    for (int g2 = 0; g2 < 2; ++g2) {
      const int tok = g2*16 + fr;
      hf2[g2] = *(const bf16x8*)((const char*)Hw + tok*64 + ((fg ^ hxor) << 4));
    }
    #pragma unroll
    for (int nf = 0; nf < 16; ++nf) {
      const int n = nf*16 + fr;
      bf16x8 w2f = *(const bf16x8*)&W2s[cur][n*32 + ((fg ^ ((n >> 1) & 3)) << 3)];
      acc2[0][nf] = __builtin_amdgcn_mfma_f32_16x16x32_bf16(hf2[0], w2f, acc2[0][nf], 0, 0, 0);
      acc2[1][nf] = __builtin_amdgcn_mfma_f32_16x16x32_bf16(hf2[1], w2f, acc2[1][nf], 0, 0, 0);
    }
  };

  stage(0);
  stage(1);
  for (int t = 0; t < 30; ++t) {
    __builtin_amdgcn_s_barrier();                      // protects restage below
    stage(t + 2);                                      // depth-2 prefetch
    asm volatile("s_waitcnt vmcnt(8)" ::: "memory");   // stage(t) landed
    __builtin_amdgcn_s_setprio(1);
    gemm1(t);
    if (t > 0) gemm2(t - 1);
    __builtin_amdgcn_s_setprio(0);
  }
  __builtin_amdgcn_s_barrier();
  asm volatile("s_waitcnt vmcnt(4)" ::: "memory");     // tail: slice 30
  __builtin_amdgcn_s_setprio(1);
  gemm1(30); gemm2(29);
  __builtin_amdgcn_s_setprio(0);
  __builtin_amdgcn_s_barrier();
  asm volatile("s_waitcnt vmcnt(0)" ::: "memory");     // tail: slice 31
  __builtin_amdgcn_s_setprio(1);
  gemm1(31); gemm2(30);
  gemm2(31);                                           // drain lag
  __builtin_amdgcn_s_setprio(0);

  // epilogue: bias2 + residual + LayerNorm, per row-group
  #pragma unroll
  for (int g2 = 0; g2 < 2; ++g2) {
    const int rbase = row0 + g2*16 + fg*4;
    float s1[4] = {}, sq[4] = {};
    #pragma unroll
    for (int nf = 0; nf < 16; ++nf) {
      const int c = nf*16 + fr;
      const float b = b2[c];
      #pragma unroll
      for (int t = 0; t < 4; ++t) {
        float v = acc2[g2][nf][t] + b + bf2f(X[(size_t)(rbase + t) * 256 + c]);
        acc2[g2][nf][t] = v;
        s1[t] += v; sq[t] += v * v;
      }
    }
    #pragma unroll
    for (int d = 1; d < 16; d <<= 1) {
      #pragma unroll
      for (int t = 0; t < 4; ++t) {
        s1[t] += __shfl_xor(s1[t], d, 64);
        sq[t] += __shfl_xor(sq[t], d, 64);
      }
    }
    float mean[4], rstd[4];
    #pragma unroll
    for (int t = 0; t < 4; ++t) {
      mean[t] = s1[t] * (1.f/256.f);
      const float var = sq[t] * (1.f/256.f) - mean[t]*mean[t];
      rstd[t] = rsqrtf(var + 1e-5f);
    }
    #pragma unroll
    for (int nf = 0; nf < 16; ++nf) {
      const int c = nf*16 + fr;
      const float gc = g[c], bc = be[c];
      #pragma unroll
      for (int t = 0; t < 4; ++t) {
        const float y = (acc2[g2][nf][t] - mean[t]) * rstd[t] * gc + bc;
        if (OUT_F32) ((float*)Y)[(size_t)(rbase + t) * 256 + c] = y;
        else         ((u16*)Y)[(size_t)(rbase + t) * 256 + c] = f2bf(y);
      }
    }
  }
}

// ---------------------------------------------------------------------------
// MFMA windowed attention. One wave per window (4 waves/block, no block
// barriers). Per head: S=QK^T via 4 mfma, softmax in C-layout (shfl_xor over
// 16-lane fr group, normalization deferred), P -> wave-private LDS -> A-frags,
// O=PV via 4 mfma with B-frags from window-transposed Vt[win][dim][key].
// O may alias Q (per head, Q cols read before O cols stored).
// ---------------------------------------------------------------------------
__global__ __launch_bounds__(256) void attn_mfma(
    const u16* Q, int sq, const u16* __restrict__ K, int sk,
    const u16* __restrict__ Vt, u16* O, int so)
{
  __shared__ u16 P[4][32 * 40];
  const int tid = threadIdx.x, lane = tid & 63, w = tid >> 6;
  const int win = blockIdx.x * 4 + w;
  const size_t q0 = (size_t)win * 32;
  const int fr = lane & 15, fg = lane >> 4;
  u16* Pw = &P[w][0];
  const float scale = 0.17677669529663687f;   // 1/sqrt(32)

  for (int h = 0; h < 8; ++h) {
    const int co = h * 32;
    bf16x8 qa[2], kb[2];
    #pragma unroll
    for (int i = 0; i < 2; ++i)
      qa[i] = *(const bf16x8*)&Q[(q0 + i*16 + fr) * sq + co + fg*8];
    #pragma unroll
    for (int j = 0; j < 2; ++j)
      kb[j] = *(const bf16x8*)&K[(q0 + j*16 + fr) * sk + co + fg*8];
    f32x4 s[2][2] = {};
    #pragma unroll
    for (int i = 0; i < 2; ++i)
      #pragma unroll
      for (int j = 0; j < 2; ++j)
        s[i][j] = __builtin_amdgcn_mfma_f32_16x16x32_bf16(qa[i], kb[j], s[i][j], 0, 0, 0);

    float inv[2][4];
    #pragma unroll
    for (int i = 0; i < 2; ++i) {
      #pragma unroll
      for (int t = 0; t < 4; ++t) {
        float a0 = s[i][0][t] * scale, a1 = s[i][1][t] * scale;
        float mx = fmaxf(a0, a1);
        #pragma unroll
        for (int d = 1; d < 16; d <<= 1) mx = fmaxf(mx, __shfl_xor(mx, d, 64));
        const float p0 = __expf(a0 - mx), p1 = __expf(a1 - mx);
        float sm = p0 + p1;
        #pragma unroll
        for (int d = 1; d < 16; d <<= 1) sm += __shfl_xor(sm, d, 64);
        inv[i][t] = 1.f / sm;
        const int q = i*16 + fg*4 + t;
        Pw[q*40 + fr]      = f2bf(p0);
        Pw[q*40 + 16 + fr] = f2bf(p1);
      }
    }

    bf16x8 pa[2], vb[2];
    #pragma unroll
    for (int i = 0; i < 2; ++i)
      pa[i] = *(const bf16x8*)&Pw[(i*16 + fr)*40 + fg*8];
    #pragma unroll
    for (int j = 0; j < 2; ++j)
      vb[j] = *(const bf16x8*)&Vt[(size_t)win*8192 + (co + j*16 + fr)*32 + fg*8];
    f32x4 oacc[2][2] = {};
    #pragma unroll
    for (int i = 0; i < 2; ++i)
      #pragma unroll
      for (int j = 0; j < 2; ++j)
        oacc[i][j] = __builtin_amdgcn_mfma_f32_16x16x32_bf16(pa[i], vb[j], oacc[i][j], 0, 0, 0);

    #pragma unroll
    for (int i = 0; i < 2; ++i)
      #pragma unroll
      for (int j = 0; j < 2; ++j)
        #pragma unroll
        for (int t = 0; t < 4; ++t)
          O[(q0 + i*16 + fg*4 + t) * so + co + j*16 + fr] =
              f2bf(oacc[i][j][t] * inv[i][t]);
  }
}

// ---------------------------------------------------------------------------
__global__ __launch_bounds__(256) void wprep(
    const float* __restrict__ W, u16* __restrict__ Wt, int K, int N)
{
  const int idx = blockIdx.x * 256 + threadIdx.x;
  if (idx >= K * N) return;
  const int k = idx / N, n = idx - k * N;
  Wt[(size_t)n * K + k] = f2bf(W[idx]);
}

__global__ __launch_bounds__(256) void bcat(
    const float* __restrict__ a, const float* __restrict__ b,
    const float* __restrict__ c, float* __restrict__ o)
{
  const int i = blockIdx.x * 256 + threadIdx.x;
  o[i] = i < 256 ? a[i] : (i < 512 ? b[i - 256] : c[i - 512]);
}

// ---------------------------------------------------------------------------
extern "C" void kernel_launch(void* const* d_in, const int* in_sizes, int n_in,
                              void* d_out, int out_size, void* d_ws, size_t ws_size,
                              hipStream_t stream)
{
  const float* query  = (const float*)d_in[0];
  const float* keyval = (const float*)d_in[1];
  const float* Wq = (const float*)d_in[2];  const float* bq  = (const float*)d_in[3];
  const float* Wk = (const float*)d_in[4];  const float* bk  = (const float*)d_in[5];
  const float* Wv = (const float*)d_in[6];  const float* bv  = (const float*)d_in[7];
  const float* Wo = (const float*)d_in[8];  const float* bo  = (const float*)d_in[9];
  const float* g1 = (const float*)d_in[10]; const float* be1 = (const float*)d_in[11];
  const float* W1 = (const float*)d_in[12]; const float* bf1 = (const float*)d_in[13];
  const float* W2 = (const float*)d_in[14]; const float* bf2 = (const float*)d_in[15];
  const float* g2 = (const float*)d_in[16]; const float* be2 = (const float*)d_in[17];

  const int M = 131072;      // B*L token rows
  char* ws = (char*)d_ws;
  // Workspace (<=450 MiB of 512 MiB d_ws):
  //   [0,64)     xcur bf16 [M][256]   (layer-2 input, written by L1 ffn)
  //   [64,128)   x1   bf16 [M][256]
  //   [256,384)  QKc  bf16 [M][512]   (Q | K cols; attn O in place over Q)
  //   [384,448)  Vtc  bf16 [4096 win][256][32]  (window-transposed V)
  //   [448,..)   bf16 weights + fused qkv bias
  u16*  xcur = (u16*)ws;
  u16*  x1   = (u16*)(ws + (64ull  << 20));
  u16*  QKc  = (u16*)(ws + (256ull << 20));
  u16*  Vtc  = (u16*)(ws + (384ull << 20));
  u16*  WqkvT = (u16*)(ws + (448ull << 20));   // [768][256] = Wq|Wk|Wv rows
  u16*  WoT   = WqkvT + 196608;                // [256][256]
  u16*  W1T   = WoT   + 65536;                 // [1024][256]
  u16*  W2T   = W1T   + 262144;                // [256][1024]
  float* bqkv = (float*)(W2T + 262144);        // [768]
  float* bkv  = bqkv + 256;                    // [512] = bk|bv

  wprep<<<256,  256, 0, stream>>>(Wq, WqkvT,          256, 256);
  wprep<<<256,  256, 0, stream>>>(Wk, WqkvT +  65536, 256, 256);
  wprep<<<256,  256, 0, stream>>>(Wv, WqkvT + 131072, 256, 256);
  wprep<<<256,  256, 0, stream>>>(Wo, WoT, 256, 256);
  wprep<<<1024, 256, 0, stream>>>(W1, W1T, 256, 1024);
  wprep<<<1024, 256, 0, stream>>>(W2, W2T, 1024, 256);
  bcat<<<3, 256, 0, stream>>>(bq, bk, bv, bqkv);

  // NOTE: jnp.roll(x, -16, axis=1) permutes whole windows; the encoder layer is
  // window-local and position-independent, so roll + layer + unroll == layer.
  // Both rolls are elided (bit-exact equivalence).

  // ---- layer 1: A inputs are raw fp32 (converted during GEMM staging) ----
  gemm_bt<0,1><<<2048, 256, 0, stream>>>(
      query, 256, WqkvT, bq, QKc, 512, 0, nullptr, 0, 256, 256, 2);
  gemm_bt<2,1><<<4096, 256, 0, stream>>>(
      keyval, 256, WqkvT + 65536, bkv, QKc, 512, 256, Vtc, 256, 512, 256, 4);
  attn_mfma<<<1024, 256, 0, stream>>>(QKc, 512, QKc + 256, 512, Vtc, QKc, 512);
  gemm_oln<1><<<1024, 512, 0, stream>>>(
      QKc, 512, WoT, bo, query, g1, be1, x1, 256);        // residual = fp32 query
  ffn_fused<0><<<512, 512, 0, stream>>>(
      x1, W1T, bf1, W2T, bf2, g2, be2, xcur);

  // ---- layer 2: q = kv = xcur (bf16) ----
  gemm_bt<2,0><<<6144, 256, 0, stream>>>(
      xcur, 256, WqkvT, bqkv, QKc, 512, 0, Vtc, 512, 768, 256, 6);
  attn_mfma<<<1024, 256, 0, stream>>>(QKc, 512, QKc + 256, 512, Vtc, QKc, 512);
  gemm_oln<0><<<1024, 512, 0, stream>>>(
      QKc, 512, WoT, bo, xcur, g1, be1, x1, 256);         // residual = bf16 xcur
  ffn_fused<1><<<512, 512, 0, stream>>>(
      x1, W1T, bf1, W2T, bf2, g2, be2, d_out);
}

// Round 18
// 895.688 us; speedup vs baseline: 1.0463x; 1.0463x over previous
//
#include <hip/hip_runtime.h>
#include <cstdint>
#include <cstddef>

typedef unsigned short u16;
typedef __bf16 bf16x8 __attribute__((ext_vector_type(8)));
typedef float f32x4 __attribute__((ext_vector_type(4)));
typedef unsigned short u16x8 __attribute__((ext_vector_type(8)));
typedef unsigned short u16x4 __attribute__((ext_vector_type(4)));

__device__ __forceinline__ u16 f2bf(float f) {
  union { float f; unsigned u; } x; x.f = f;
  unsigned r = x.u + 0x7fffu + ((x.u >> 16) & 1u);   // RNE
  return (u16)(r >> 16);
}
__device__ __forceinline__ float bf2f(u16 u) {
  union { unsigned u; float f; } x; x.u = ((unsigned)u) << 16;
  return x.f;
}
// async global->LDS, 16B/lane; LDS dest = wave-uniform base + lane*16 (linear)
__device__ __forceinline__ void gload16(const void* g, void* l) {
  __builtin_amdgcn_global_load_lds(
      (const __attribute__((address_space(1))) unsigned int*)g,
      (__attribute__((address_space(3))) unsigned int*)l, 16, 0, 0);
}

// ---------------------------------------------------------------------------
// GEMM: C = A[.][K](lda) @ Bt^T + bias. Bt[N][K] bf16. 128x128 tile, BK=32,
// 4 waves, 2-phase double-buffered (prefetch before compute, one barrier per
// K-step). Slot swizzle slot^(row&3) both sides. 1-D grid, col-fastest +
// bijective XCD chunking (nwg%8==0).
// AF32=0: A bf16, global_load_lds staging.
// AF32=1: A fp32, T14 split staging: f32 loads issued BEFORE compute,
//         convert + swizzled ds_write AFTER compute (hides HBM latency).
// MODE 0: natural bf16 out C0[r*ldc + coff + c];  MODE 1: + ReLU
// MODE 2: split route: col<vsplit natural into C0 (+coff);
//         col>=vsplit window-transposed into C2[win][c-vsplit][tok&31]
// MODE 3: pure window-transposed into C2[win][c][tok&31]
// ---------------------------------------------------------------------------
template<int MODE, int AF32>
__global__ __launch_bounds__(256) void gemm_bt(
    const void* __restrict__ Ap_, int lda, const u16* __restrict__ Bt,
    const float* __restrict__ bias, u16* __restrict__ C0, int ldc, int coff,
    u16* __restrict__ C2, int vsplit, int N, int K, int gy)
{
  __shared__ u16 As[2][128 * 32];
  __shared__ u16 Bs[2][128 * 32];
  const int tid  = threadIdx.x;
  const int lane = tid & 63, w = tid >> 6;
  const int nwg = gridDim.x, o = blockIdx.x;
  const int lid = (o & 7) * (nwg >> 3) + (o >> 3);   // contiguous lid -> same XCD
  const int by = lid % gy, bx = lid / gy;
  const int row0 = bx * 128, col0 = by * 128;
  const int wr = (w >> 1) * 64, wc = (w & 1) * 64;
  const int fr = lane & 15, fg = lane >> 4;          // fragment row / k-group
  const int srow  = (w << 5) + (lane >> 2);
  const int sslot = (lane & 3) ^ ((lane >> 2) & 3);
  const u16*   Ab = (const u16*)Ap_;
  const float* Af = (const float*)Ap_;

  auto stageB = [&](int buf, int k0) {
    #pragma unroll
    for (int h = 0; h < 2; ++h)
      gload16((const char*)Bt + ((size_t)(col0 + srow + h*16) * K + k0) * 2 + sslot*16,
              &Bs[buf][((w << 5) + h*16) * 32]);
  };
  auto stageA16 = [&](int buf, int k0) {
    #pragma unroll
    for (int h = 0; h < 2; ++h)
      gload16((const char*)Ab + ((size_t)(row0 + srow + h*16) * lda + k0) * 2 + sslot*16,
              &As[buf][((w << 5) + h*16) * 32]);
  };
  // fp32 A: 512 slots (128 rows x 4 slots of 8 values); 2 slots/thread
  f32x4 pre[2][2];
  auto loadA32 = [&](int k0) {
    #pragma unroll
    for (int p = 0; p < 2; ++p) {
      const int sidx = tid + p*256, rr = sidx >> 2, sl = sidx & 3;
      const float* src = &Af[(size_t)(row0 + rr) * lda + k0 + sl*8];
      pre[p][0] = *(const f32x4*)src;
      pre[p][1] = *(const f32x4*)(src + 4);
    }
  };
  auto writeA32 = [&](int buf) {
    #pragma unroll
    for (int p = 0; p < 2; ++p) {
      const int sidx = tid + p*256, rr = sidx >> 2, sl = sidx & 3;
      u16x8 o = { f2bf(pre[p][0][0]), f2bf(pre[p][0][1]),
                  f2bf(pre[p][0][2]), f2bf(pre[p][0][3]),
                  f2bf(pre[p][1][0]), f2bf(pre[p][1][1]),
                  f2bf(pre[p][1][2]), f2bf(pre[p][1][3]) };
      *(u16x8*)&As[buf][rr*32 + ((sl ^ (rr & 3)) << 3)] = o;
    }
  };

  f32x4 acc[4][4] = {};

  if (AF32) { loadA32(0); stageB(0, 0); writeA32(0); }
  else      { stageA16(0, 0); stageB(0, 0); }
  __syncthreads();                  // prologue drain (vm + lgkm)
  int cur = 0;
  for (int k0 = 0; k0 < K; k0 += 32) {
    const int has_next = (k0 + 32 < K);
    if (has_next) {                 // issue next-tile loads before compute
      if (AF32) loadA32(k0 + 32);
      else      stageA16(cur ^ 1, k0 + 32);
      stageB(cur ^ 1, k0 + 32);
    }
    bf16x8 af[4], bf[4];
    #pragma unroll
    for (int i = 0; i < 4; ++i) {
      const int r = wr + i*16 + fr;
      af[i] = *(const bf16x8*)&As[cur][r*32 + ((fg ^ (fr & 3)) << 3)];
    }
    #pragma unroll
    for (int j = 0; j < 4; ++j) {
      const int r = wc + j*16 + fr;
      bf[j] = *(const bf16x8*)&Bs[cur][r*32 + ((fg ^ (fr & 3)) << 3)];
    }
    #pragma unroll
    for (int i = 0; i < 4; ++i)
      #pragma unroll
      for (int j = 0; j < 4; ++j)
        acc[i][j] = __builtin_amdgcn_mfma_f32_16x16x32_bf16(af[i], bf[j], acc[i][j], 0, 0, 0);
    if (AF32 && has_next) writeA32(cur ^ 1);   // T14: write-late
    __syncthreads();                // all reads done + next stage drained
    cur ^= 1;
  }

  // epilogue: D[row=fg*4+t][col=fr] per 16x16 fragment (m89-verified mapping)
  const int vpart = (MODE == 3) || (MODE == 2 && col0 >= vsplit);  // wave-uniform
  #pragma unroll
  for (int j = 0; j < 4; ++j) {
    const int c  = col0 + wc + j*16 + fr;
    const float bv = bias[c];
    #pragma unroll
    for (int i = 0; i < 4; ++i) {
      if (vpart) {
        const int cv = (MODE == 2) ? c - vsplit : c;
        const int rb = row0 + wr + i*16 + fg*4;   // 4 consecutive tokens
        u16x4 vv;
        #pragma unroll
        for (int t = 0; t < 4; ++t) vv[t] = f2bf(acc[i][j][t] + bv);
        *(u16x4*)&C2[((size_t)(rb >> 5) * 256 + cv) * 32 + (rb & 31)] = vv;
      } else {
        #pragma unroll
        for (int t = 0; t < 4; ++t) {
          const int r = row0 + wr + i*16 + fg*4 + t;
          float v = acc[i][j][t] + bv;
          if (MODE == 1) v = v > 0.f ? v : 0.f;
          C0[(size_t)r * ldc + coff + c] = f2bf(v);
        }
      }
    }
  }
}

// ---------------------------------------------------------------------------
// O-proj + bias + residual + LayerNorm fused (full-row tile).
// 128 rows x 256 cols per block, 8 waves (2 row x 4 col of 64x64), BK=32.
// RES_F32: residual read as fp32 (layer 1: raw query) or bf16 (layer 2).
// ---------------------------------------------------------------------------
template<int RES_F32>
__global__ __launch_bounds__(512) void gemm_oln(
    const u16* __restrict__ Ap, int lda, const u16* __restrict__ Bt,
    const float* __restrict__ bias, const void* __restrict__ Res,
    const float* __restrict__ g, const float* __restrict__ be,
    u16* __restrict__ Y, int K)
{
  __shared__ u16 As[2][128 * 32];    // 8 KB x2
  __shared__ u16 Bs[2][256 * 32];    // 16 KB x2
  __shared__ float2 red[128][4];     // 4 KB
  __shared__ float2 stats[128];      // 1 KB
  const int tid  = threadIdx.x;
  const int lane = tid & 63, w = tid >> 6;
  const int nwg = gridDim.x, o = blockIdx.x;
  const int lid = (o & 7) * (nwg >> 3) + (o >> 3);   // XCD chunk
  const int row0 = lid * 128;
  const int wr = (w >> 2) * 64, wc = (w & 3) * 64;
  const int fr = lane & 15, fg = lane >> 4;
  const int sr   = lane >> 2;
  const int sslot = (lane & 3) ^ ((lane >> 2) & 3);

  auto stage = [&](int buf, int k0) {
    gload16((const char*)Ap + ((size_t)(row0 + (w << 4) + sr) * lda + k0) * 2 + sslot*16,
            &As[buf][((w << 4)) * 32]);
    #pragma unroll
    for (int h = 0; h < 2; ++h)
      gload16((const char*)Bt + ((size_t)((w << 5) + h*16 + sr) * K + k0) * 2 + sslot*16,
              &Bs[buf][((w << 5) + h*16) * 32]);
  };

  f32x4 acc[4][4] = {};

  stage(0, 0);
  __syncthreads();
  int cur = 0;
  for (int k0 = 0; k0 < K; k0 += 32) {
    if (k0 + 32 < K) stage(cur ^ 1, k0 + 32);
    bf16x8 af[4], bf[4];
    #pragma unroll
    for (int i = 0; i < 4; ++i) {
      const int r = wr + i*16 + fr;
      af[i] = *(const bf16x8*)&As[cur][r*32 + ((fg ^ (fr & 3)) << 3)];
    }
    #pragma unroll
    for (int j = 0; j < 4; ++j) {
      const int r = wc + j*16 + fr;
      bf[j] = *(const bf16x8*)&Bs[cur][r*32 + ((fg ^ (fr & 3)) << 3)];
    }
    #pragma unroll
    for (int i = 0; i < 4; ++i)
      #pragma unroll
      for (int j = 0; j < 4; ++j)
        acc[i][j] = __builtin_amdgcn_mfma_f32_16x16x32_bf16(af[i], bf[j], acc[i][j], 0, 0, 0);
    __syncthreads();
    cur ^= 1;
  }

  // epilogue: v = acc + bias + residual; row stats; LN; store
  float ps[4][4] = {}, pq[4][4] = {};
  #pragma unroll
  for (int j = 0; j < 4; ++j) {
    const int c = wc + j*16 + fr;
    const float bv = bias[c];
    #pragma unroll
    for (int i = 0; i < 4; ++i) {
      #pragma unroll
      for (int t = 0; t < 4; ++t) {
        const int r = row0 + wr + i*16 + fg*4 + t;
        const float rv = RES_F32 ? ((const float*)Res)[(size_t)r * 256 + c]
                                 : bf2f(((const u16*)Res)[(size_t)r * 256 + c]);
        float v = acc[i][j][t] + bv + rv;
        acc[i][j][t] = v;
        ps[i][t] += v;
        pq[i][t] += v * v;
      }
    }
  }
  #pragma unroll
  for (int d = 1; d < 16; d <<= 1) {
    #pragma unroll
    for (int i = 0; i < 4; ++i)
      #pragma unroll
      for (int t = 0; t < 4; ++t) {
        ps[i][t] += __shfl_xor(ps[i][t], d, 64);
        pq[i][t] += __shfl_xor(pq[i][t], d, 64);
      }
  }
  if (fr == 0) {
    #pragma unroll
    for (int i = 0; i < 4; ++i)
      #pragma unroll
      for (int t = 0; t < 4; ++t)
        red[wr + i*16 + fg*4 + t][w & 3] = make_float2(ps[i][t], pq[i][t]);
  }
  __syncthreads();
  if (tid < 128) {
    float S = 0.f, Q = 0.f;
    #pragma unroll
    for (int ww = 0; ww < 4; ++ww) { float2 p = red[tid][ww]; S += p.x; Q += p.y; }
    const float m = S * (1.f/256.f);
    const float var = Q * (1.f/256.f) - m*m;
    stats[tid] = make_float2(m, rsqrtf(var + 1e-5f));
  }
  __syncthreads();
  #pragma unroll
  for (int i = 0; i < 4; ++i) {
    #pragma unroll
    for (int t = 0; t < 4; ++t) {
      const int rl = wr + i*16 + fg*4 + t;
      const float2 st = stats[rl];
      const size_t r = row0 + rl;
      #pragma unroll
      for (int j = 0; j < 4; ++j) {
        const int c = wc + j*16 + fr;
        Y[r * 256 + c] = f2bf((acc[i][j][t] - st.x) * st.y * g[c] + be[c]);
      }
    }
  }
}

// ---------------------------------------------------------------------------
// Fused FFN v4 (reverted from v5; v5's lag-1 pipeline regressed 170->189us):
// Y = LayerNorm( X + relu(X@W1 + bf1)@W2 + bf2 ; g,be ).
// K32 GEMM2 via wave-private LDS H-bounce + T4 counted-vmcnt pipeline:
// 4 weight buffers, depth-2 prefetch, raw s_barrier, s_waitcnt vmcnt(8)
// steady state (never 0; tail peels 4 -> 0). Stage issued BEFORE the
// wait+barrier pair (the fine interleave IS the asset — m196 lesson).
// 256-row blocks, 8 waves x 32 rows (2 row-groups; W frags feed 2 mfma each).
// ---------------------------------------------------------------------------
template<int OUT_F32>
__global__ __launch_bounds__(512, 2) void ffn_fused(
    const u16* __restrict__ X, const u16* __restrict__ W1T,
    const float* __restrict__ b1, const u16* __restrict__ W2T,
    const float* __restrict__ b2, const float* __restrict__ g,
    const float* __restrict__ be, void* __restrict__ Y)
{
  __shared__ u16 W1s[4][32 * 256];   // [h 32][k 256], granule ^= row&7
  __shared__ u16 W2s[4][256 * 32];   // [n 256][k 32], granule ^= (row>>1)&3
  __shared__ u16 Hs[8][32 * 32];     // per-wave [tok 32][h 32], 64B rows
  __shared__ float b1s[1024];
  const int tid = threadIdx.x, lane = tid & 63, w = tid >> 6;
  const int fr = lane & 15, fg = lane >> 4;
  const int row0 = blockIdx.x * 256 + w * 32;
  u16* Hw = &Hs[w][0];
  const int hxor = (fr >> 1) & 3;

  auto stage = [&](int buf, int hb) {
    #pragma unroll
    for (int h = 0; h < 2; ++h) {   // W1 slice [32][256]: 2 rows/wave/issue
      const int r = w*4 + h*2 + (lane >> 5);
      const int sl = (lane & 31) ^ (r & 7);
      gload16((const char*)W1T + ((size_t)((hb << 5) + r) * 256 + sl*8) * 2,
              &W1s[buf][(w*4 + h*2) * 256]);
    }
    #pragma unroll
    for (int h = 0; h < 2; ++h) {   // W2 slice [256][32]: 16 rows/wave/issue
      const int r = w*32 + h*16 + (lane >> 2);
      const int sl = (lane & 3) ^ ((r >> 1) & 3);
      gload16((const char*)W2T + ((size_t)r * 1024 + (hb << 5) + sl*8) * 2,
              &W2s[buf][(w*32 + h*16) * 32]);
    }
  };

  if (tid < 256) {
    f32x4 bv = *(const f32x4*)&b1[tid * 4];
    *(f32x4*)&b1s[tid * 4] = bv;
  }
  bf16x8 af[2][8];
  #pragma unroll
  for (int g2 = 0; g2 < 2; ++g2)
    #pragma unroll
    for (int kf = 0; kf < 8; ++kf)
      af[g2][kf] = *(const bf16x8*)&X[(size_t)(row0 + g2*16 + fr) * 256 + kf*32 + fg*8];
  asm volatile("s_waitcnt vmcnt(0)" ::: "memory");   // af + b1 drained

  f32x4 acc2[2][16] = {};   // out rows g*16+fg*4+t, col nf*16+fr

  auto compute_slice = [&](int hb, int cur) {
    f32x4 acc1[2][2] = {};   // [hf][g]
    #pragma unroll
    for (int kf = 0; kf < 8; ++kf) {
      #pragma unroll
      for (int hf = 0; hf < 2; ++hf) {
        const int n = hf*16 + fr;
        bf16x8 w1f = *(const bf16x8*)&W1s[cur][n*256 + ((((kf << 2) | fg) ^ (n & 7)) << 3)];
        acc1[hf][0] = __builtin_amdgcn_mfma_f32_16x16x32_bf16(w1f, af[0][kf], acc1[hf][0], 0, 0, 0);
        acc1[hf][1] = __builtin_amdgcn_mfma_f32_16x16x32_bf16(w1f, af[1][kf], acc1[hf][1], 0, 0, 0);
      }
    }
    #pragma unroll
    for (int g2 = 0; g2 < 2; ++g2) {
      #pragma unroll
      for (int hf = 0; hf < 2; ++hf) {
        const int h0 = hf*16 + fg*4;
        f32x4 b4 = *(const f32x4*)&b1s[(hb << 5) + h0];
        u16x4 hv;
        #pragma unroll
        for (int t = 0; t < 4; ++t) {
          float v = acc1[hf][g2][t] + b4[t];
          hv[t] = f2bf(v > 0.f ? v : 0.f);
        }
        const int tok = g2*16 + fr;
        *(u16x4*)((char*)Hw + tok*64 + ((((hf << 1) | (fg >> 1)) ^ hxor) << 4)
                                     + ((fg & 1) << 3)) = hv;
      }
    }
    asm volatile("s_waitcnt lgkmcnt(0)" ::: "memory");   // cross-lane H hazard
    __builtin_amdgcn_sched_barrier(0);                   // rule #18

    bf16x8 hf2[2];
    #pragma unroll
    for (int g2 = 0; g2 < 2; ++g2) {
      const int tok = g2*16 + fr;
      hf2[g2] = *(const bf16x8*)((char*)Hw + tok*64 + ((fg ^ hxor) << 4));
    }
    #pragma unroll
    for (int nf = 0; nf < 16; ++nf) {
      const int n = nf*16 + fr;
      bf16x8 w2f = *(const bf16x8*)&W2s[cur][n*32 + ((fg ^ ((n >> 1) & 3)) << 3)];
      acc2[0][nf] = __builtin_amdgcn_mfma_f32_16x16x32_bf16(hf2[0], w2f, acc2[0][nf], 0, 0, 0);
      acc2[1][nf] = __builtin_amdgcn_mfma_f32_16x16x32_bf16(hf2[1], w2f, acc2[1][nf], 0, 0, 0);
    }
  };

  stage(0, 0);
  stage(1, 1);
  for (int hb = 0; hb < 30; ++hb) {
    stage((hb + 2) & 3, hb + 2);                       // depth-2 prefetch
    asm volatile("s_waitcnt vmcnt(8)" ::: "memory");   // cur-slice loads done
    __builtin_amdgcn_s_barrier();
    __builtin_amdgcn_sched_barrier(0);
    compute_slice(hb, hb & 3);
  }
  asm volatile("s_waitcnt vmcnt(4)" ::: "memory");     // tail: slice 30
  __builtin_amdgcn_s_barrier();
  __builtin_amdgcn_sched_barrier(0);
  compute_slice(30, 30 & 3);
  asm volatile("s_waitcnt vmcnt(0)" ::: "memory");     // tail: slice 31
  __builtin_amdgcn_s_barrier();
  __builtin_amdgcn_sched_barrier(0);
  compute_slice(31, 31 & 3);

  // epilogue: bias2 + residual + LayerNorm, per row-group
  #pragma unroll
  for (int g2 = 0; g2 < 2; ++g2) {
    const int rbase = row0 + g2*16 + fg*4;
    float s1[4] = {}, sq[4] = {};
    #pragma unroll
    for (int nf = 0; nf < 16; ++nf) {
      const int c = nf*16 + fr;
      const float b = b2[c];
      #pragma unroll
      for (int t = 0; t < 4; ++t) {
        float v = acc2[g2][nf][t] + b + bf2f(X[(size_t)(rbase + t) * 256 + c]);
        acc2[g2][nf][t] = v;
        s1[t] += v; sq[t] += v * v;
      }
    }
    #pragma unroll
    for (int d = 1; d < 16; d <<= 1) {
      #pragma unroll
      for (int t = 0; t < 4; ++t) {
        s1[t] += __shfl_xor(s1[t], d, 64);
        sq[t] += __shfl_xor(sq[t], d, 64);
      }
    }
    float mean[4], rstd[4];
    #pragma unroll
    for (int t = 0; t < 4; ++t) {
      mean[t] = s1[t] * (1.f/256.f);
      const float var = sq[t] * (1.f/256.f) - mean[t]*mean[t];
      rstd[t] = rsqrtf(var + 1e-5f);
    }
    #pragma unroll
    for (int nf = 0; nf < 16; ++nf) {
      const int c = nf*16 + fr;
      const float gc = g[c], bc = be[c];
      #pragma unroll
      for (int t = 0; t < 4; ++t) {
        const float y = (acc2[g2][nf][t] - mean[t]) * rstd[t] * gc + bc;
        if (OUT_F32) ((float*)Y)[(size_t)(rbase + t) * 256 + c] = y;
        else         ((u16*)Y)[(size_t)(rbase + t) * 256 + c] = f2bf(y);
      }
    }
  }
}

// ---------------------------------------------------------------------------
// MFMA windowed attention. One wave per window (4 waves/block, no block
// barriers). Per head: S=QK^T via 4 mfma, softmax in C-layout (shfl_xor over
// 16-lane fr group, normalization deferred), P -> wave-private LDS -> A-frags,
// O=PV via 4 mfma with B-frags from window-transposed Vt[win][dim][key].
// O may alias Q (per head, Q cols read before O cols stored).
// ---------------------------------------------------------------------------
__global__ __launch_bounds__(256) void attn_mfma(
    const u16* Q, int sq, const u16* __restrict__ K, int sk,
    const u16* __restrict__ Vt, u16* O, int so)
{
  __shared__ u16 P[4][32 * 40];
  const int tid = threadIdx.x, lane = tid & 63, w = tid >> 6;
  const int win = blockIdx.x * 4 + w;
  const size_t q0 = (size_t)win * 32;
  const int fr = lane & 15, fg = lane >> 4;
  u16* Pw = &P[w][0];
  const float scale = 0.17677669529663687f;   // 1/sqrt(32)

  for (int h = 0; h < 8; ++h) {
    const int co = h * 32;
    bf16x8 qa[2], kb[2];
    #pragma unroll
    for (int i = 0; i < 2; ++i)
      qa[i] = *(const bf16x8*)&Q[(q0 + i*16 + fr) * sq + co + fg*8];
    #pragma unroll
    for (int j = 0; j < 2; ++j)
      kb[j] = *(const bf16x8*)&K[(q0 + j*16 + fr) * sk + co + fg*8];
    f32x4 s[2][2] = {};
    #pragma unroll
    for (int i = 0; i < 2; ++i)
      #pragma unroll
      for (int j = 0; j < 2; ++j)
        s[i][j] = __builtin_amdgcn_mfma_f32_16x16x32_bf16(qa[i], kb[j], s[i][j], 0, 0, 0);

    float inv[2][4];
    #pragma unroll
    for (int i = 0; i < 2; ++i) {
      #pragma unroll
      for (int t = 0; t < 4; ++t) {
        float a0 = s[i][0][t] * scale, a1 = s[i][1][t] * scale;
        float mx = fmaxf(a0, a1);
        #pragma unroll
        for (int d = 1; d < 16; d <<= 1) mx = fmaxf(mx, __shfl_xor(mx, d, 64));
        const float p0 = __expf(a0 - mx), p1 = __expf(a1 - mx);
        float sm = p0 + p1;
        #pragma unroll
        for (int d = 1; d < 16; d <<= 1) sm += __shfl_xor(sm, d, 64);
        inv[i][t] = 1.f / sm;
        const int q = i*16 + fg*4 + t;
        Pw[q*40 + fr]      = f2bf(p0);
        Pw[q*40 + 16 + fr] = f2bf(p1);
      }
    }

    bf16x8 pa[2], vb[2];
    #pragma unroll
    for (int i = 0; i < 2; ++i)
      pa[i] = *(const bf16x8*)&Pw[(i*16 + fr)*40 + fg*8];
    #pragma unroll
    for (int j = 0; j < 2; ++j)
      vb[j] = *(const bf16x8*)&Vt[(size_t)win*8192 + (co + j*16 + fr)*32 + fg*8];
    f32x4 oacc[2][2] = {};
    #pragma unroll
    for (int i = 0; i < 2; ++i)
      #pragma unroll
      for (int j = 0; j < 2; ++j)
        oacc[i][j] = __builtin_amdgcn_mfma_f32_16x16x32_bf16(pa[i], vb[j], oacc[i][j], 0, 0, 0);

    #pragma unroll
    for (int i = 0; i < 2; ++i)
      #pragma unroll
      for (int j = 0; j < 2; ++j)
        #pragma unroll
        for (int t = 0; t < 4; ++t)
          O[(q0 + i*16 + fg*4 + t) * so + co + j*16 + fr] =
              f2bf(oacc[i][j][t] * inv[i][t]);
  }
}

// ---------------------------------------------------------------------------
__global__ __launch_bounds__(256) void wprep(
    const float* __restrict__ W, u16* __restrict__ Wt, int K, int N)
{
  const int idx = blockIdx.x * 256 + threadIdx.x;
  if (idx >= K * N) return;
  const int k = idx / N, n = idx - k * N;
  Wt[(size_t)n * K + k] = f2bf(W[idx]);
}

__global__ __launch_bounds__(256) void bcat(
    const float* __restrict__ a, const float* __restrict__ b,
    const float* __restrict__ c, float* __restrict__ o)
{
  const int i = blockIdx.x * 256 + threadIdx.x;
  o[i] = i < 256 ? a[i] : (i < 512 ? b[i - 256] : c[i - 512]);
}

// ---------------------------------------------------------------------------
extern "C" void kernel_launch(void* const* d_in, const int* in_sizes, int n_in,
                              void* d_out, int out_size, void* d_ws, size_t ws_size,
                              hipStream_t stream)
{
  const float* query  = (const float*)d_in[0];
  const float* keyval = (const float*)d_in[1];
  const float* Wq = (const float*)d_in[2];  const float* bq  = (const float*)d_in[3];
  const float* Wk = (const float*)d_in[4];  const float* bk  = (const float*)d_in[5];
  const float* Wv = (const float*)d_in[6];  const float* bv  = (const float*)d_in[7];
  const float* Wo = (const float*)d_in[8];  const float* bo  = (const float*)d_in[9];
  const float* g1 = (const float*)d_in[10]; const float* be1 = (const float*)d_in[11];
  const float* W1 = (const float*)d_in[12]; const float* bf1 = (const float*)d_in[13];
  const float* W2 = (const float*)d_in[14]; const float* bf2 = (const float*)d_in[15];
  const float* g2 = (const float*)d_in[16]; const float* be2 = (const float*)d_in[17];

  const int M = 131072;      // B*L token rows
  char* ws = (char*)d_ws;
  // Workspace (<=450 MiB of 512 MiB d_ws):
  //   [0,64)     xcur bf16 [M][256]   (layer-2 input, written by L1 ffn)
  //   [64,128)   x1   bf16 [M][256]
  //   [256,384)  QKc  bf16 [M][512]   (Q | K cols; attn O in place over Q)
  //   [384,448)  Vtc  bf16 [4096 win][256][32]  (window-transposed V)
  //   [448,..)   bf16 weights + fused qkv bias
  u16*  xcur = (u16*)ws;
  u16*  x1   = (u16*)(ws + (64ull  << 20));
  u16*  QKc  = (u16*)(ws + (256ull << 20));
  u16*  Vtc  = (u16*)(ws + (384ull << 20));
  u16*  WqkvT = (u16*)(ws + (448ull << 20));   // [768][256] = Wq|Wk|Wv rows
  u16*  WoT   = WqkvT + 196608;                // [256][256]
  u16*  W1T   = WoT   + 65536;                 // [1024][256]
  u16*  W2T   = W1T   + 262144;                // [256][1024]
  float* bqkv = (float*)(W2T + 262144);        // [768]
  float* bkv  = bqkv + 256;                    // [512] = bk|bv

  wprep<<<256,  256, 0, stream>>>(Wq, WqkvT,          256, 256);
  wprep<<<256,  256, 0, stream>>>(Wk, WqkvT +  65536, 256, 256);
  wprep<<<256,  256, 0, stream>>>(Wv, WqkvT + 131072, 256, 256);
  wprep<<<256,  256, 0, stream>>>(Wo, WoT, 256, 256);
  wprep<<<1024, 256, 0, stream>>>(W1, W1T, 256, 1024);
  wprep<<<1024, 256, 0, stream>>>(W2, W2T, 1024, 256);
  bcat<<<3, 256, 0, stream>>>(bq, bk, bv, bqkv);

  // NOTE: jnp.roll(x, -16, axis=1) permutes whole windows; the encoder layer is
  // window-local and position-independent, so roll + layer + unroll == layer.
  // Both rolls are elided (bit-exact equivalence).

  // ---- layer 1: A inputs are raw fp32 (converted during GEMM staging) ----
  gemm_bt<0,1><<<2048, 256, 0, stream>>>(
      query, 256, WqkvT, bq, QKc, 512, 0, nullptr, 0, 256, 256, 2);
  gemm_bt<2,1><<<4096, 256, 0, stream>>>(
      keyval, 256, WqkvT + 65536, bkv, QKc, 512, 256, Vtc, 256, 512, 256, 4);
  attn_mfma<<<1024, 256, 0, stream>>>(QKc, 512, QKc + 256, 512, Vtc, QKc, 512);
  gemm_oln<1><<<1024, 512, 0, stream>>>(
      QKc, 512, WoT, bo, query, g1, be1, x1, 256);        // residual = fp32 query
  ffn_fused<0><<<512, 512, 0, stream>>>(
      x1, W1T, bf1, W2T, bf2, g2, be2, xcur);

  // ---- layer 2: q = kv = xcur (bf16) ----
  gemm_bt<2,0><<<6144, 256, 0, stream>>>(
      xcur, 256, WqkvT, bqkv, QKc, 512, 0, Vtc, 512, 768, 256, 6);
  attn_mfma<<<1024, 256, 0, stream>>>(QKc, 512, QKc + 256, 512, Vtc, QKc, 512);
  gemm_oln<0><<<1024, 512, 0, stream>>>(
      QKc, 512, WoT, bo, xcur, g1, be1, x1, 256);         // residual = bf16 xcur
  ffn_fused<1><<<512, 512, 0, stream>>>(
      x1, W1T, bf1, W2T, bf2, g2, be2, d_out);
}

// Round 19
// 882.080 us; speedup vs baseline: 1.0624x; 1.0154x over previous
//
#include <hip/hip_runtime.h>
#include <cstdint>
#include <cstddef>

typedef unsigned short u16;
typedef __bf16 bf16x8 __attribute__((ext_vector_type(8)));
typedef float f32x4 __attribute__((ext_vector_type(4)));
typedef unsigned short u16x8 __attribute__((ext_vector_type(8)));
typedef unsigned short u16x4 __attribute__((ext_vector_type(4)));

__device__ __forceinline__ u16 f2bf(float f) {
  union { float f; unsigned u; } x; x.f = f;
  unsigned r = x.u + 0x7fffu + ((x.u >> 16) & 1u);   // RNE
  return (u16)(r >> 16);
}
__device__ __forceinline__ float bf2f(u16 u) {
  union { unsigned u; float f; } x; x.u = ((unsigned)u) << 16;
  return x.f;
}
// async global->LDS, 16B/lane; LDS dest = wave-uniform base + lane*16 (linear)
__device__ __forceinline__ void gload16(const void* g, void* l) {
  __builtin_amdgcn_global_load_lds(
      (const __attribute__((address_space(1))) unsigned int*)g,
      (__attribute__((address_space(3))) unsigned int*)l, 16, 0, 0);
}

// ---------------------------------------------------------------------------
// GEMM: C = A[.][K](lda) @ Bt^T + bias. Bt[N][K] bf16. 128x128 tile, BK=32,
// 4 waves, 2-phase double-buffered (prefetch before compute, one barrier per
// K-step). Slot swizzle slot^(row&3) both sides. 1-D grid, col-fastest +
// bijective XCD chunking (nwg%8==0).
// AF32=0: A bf16, global_load_lds staging.
// AF32=1: A fp32, T14 split staging (loads before compute, convert+ds_write
//         after compute). MODE semantics as before; vsplit>=N disables vpart.
// ---------------------------------------------------------------------------
template<int MODE, int AF32>
__device__ __forceinline__ void gemm_body(
    const void* __restrict__ Ap_, int lda, const u16* __restrict__ Bt,
    const float* __restrict__ bias, u16* __restrict__ C0, int ldc, int coff,
    u16* __restrict__ C2, int vsplit, int N, int K, int gy, int nwg, int o,
    u16* As, u16* Bs)   // As: 2*128*32, Bs: 2*128*32 (LDS)
{
  const int tid  = threadIdx.x;
  const int lane = tid & 63, w = tid >> 6;
  const int lid = (o & 7) * (nwg >> 3) + (o >> 3);   // contiguous lid -> same XCD
  const int by = lid % gy, bx = lid / gy;
  const int row0 = bx * 128, col0 = by * 128;
  const int wr = (w >> 1) * 64, wc = (w & 1) * 64;
  const int fr = lane & 15, fg = lane >> 4;          // fragment row / k-group
  const int srow  = (w << 5) + (lane >> 2);
  const int sslot = (lane & 3) ^ ((lane >> 2) & 3);
  const u16*   Ab = (const u16*)Ap_;
  const float* Af = (const float*)Ap_;
  const int AB = 128 * 32;

  auto stageB = [&](int buf, int k0) {
    #pragma unroll
    for (int h = 0; h < 2; ++h)
      gload16((const char*)Bt + ((size_t)(col0 + srow + h*16) * K + k0) * 2 + sslot*16,
              &Bs[buf*AB + ((w << 5) + h*16) * 32]);
  };
  auto stageA16 = [&](int buf, int k0) {
    #pragma unroll
    for (int h = 0; h < 2; ++h)
      gload16((const char*)Ab + ((size_t)(row0 + srow + h*16) * lda + k0) * 2 + sslot*16,
              &As[buf*AB + ((w << 5) + h*16) * 32]);
  };
  f32x4 pre[2][2];
  auto loadA32 = [&](int k0) {
    #pragma unroll
    for (int p = 0; p < 2; ++p) {
      const int sidx = tid + p*256, rr = sidx >> 2, sl = sidx & 3;
      const float* src = &Af[(size_t)(row0 + rr) * lda + k0 + sl*8];
      pre[p][0] = *(const f32x4*)src;
      pre[p][1] = *(const f32x4*)(src + 4);
    }
  };
  auto writeA32 = [&](int buf) {
    #pragma unroll
    for (int p = 0; p < 2; ++p) {
      const int sidx = tid + p*256, rr = sidx >> 2, sl = sidx & 3;
      u16x8 ov = { f2bf(pre[p][0][0]), f2bf(pre[p][0][1]),
                   f2bf(pre[p][0][2]), f2bf(pre[p][0][3]),
                   f2bf(pre[p][1][0]), f2bf(pre[p][1][1]),
                   f2bf(pre[p][1][2]), f2bf(pre[p][1][3]) };
      *(u16x8*)&As[buf*AB + rr*32 + ((sl ^ (rr & 3)) << 3)] = ov;
    }
  };

  f32x4 acc[4][4] = {};

  if (AF32) { loadA32(0); stageB(0, 0); writeA32(0); }
  else      { stageA16(0, 0); stageB(0, 0); }
  __syncthreads();                  // prologue drain (vm + lgkm)
  int cur = 0;
  for (int k0 = 0; k0 < K; k0 += 32) {
    const int has_next = (k0 + 32 < K);
    if (has_next) {                 // issue next-tile loads before compute
      if (AF32) loadA32(k0 + 32);
      else      stageA16(cur ^ 1, k0 + 32);
      stageB(cur ^ 1, k0 + 32);
    }
    bf16x8 af[4], bf[4];
    #pragma unroll
    for (int i = 0; i < 4; ++i) {
      const int r = wr + i*16 + fr;
      af[i] = *(const bf16x8*)&As[cur*AB + r*32 + ((fg ^ (fr & 3)) << 3)];
    }
    #pragma unroll
    for (int j = 0; j < 4; ++j) {
      const int r = wc + j*16 + fr;
      bf[j] = *(const bf16x8*)&Bs[cur*AB + r*32 + ((fg ^ (fr & 3)) << 3)];
    }
    #pragma unroll
    for (int i = 0; i < 4; ++i)
      #pragma unroll
      for (int j = 0; j < 4; ++j)
        acc[i][j] = __builtin_amdgcn_mfma_f32_16x16x32_bf16(af[i], bf[j], acc[i][j], 0, 0, 0);
    if (AF32 && has_next) writeA32(cur ^ 1);   // T14: write-late
    __syncthreads();                // all reads done + next stage drained
    cur ^= 1;
  }

  // epilogue: D[row=fg*4+t][col=fr] per 16x16 fragment (m89-verified mapping)
  const int vpart = (MODE == 3) || (MODE == 2 && col0 >= vsplit);  // wave-uniform
  #pragma unroll
  for (int j = 0; j < 4; ++j) {
    const int c  = col0 + wc + j*16 + fr;
    const float bv = bias[c];
    #pragma unroll
    for (int i = 0; i < 4; ++i) {
      if (vpart) {
        const int cv = (MODE == 2) ? c - vsplit : c;
        const int rb = row0 + wr + i*16 + fg*4;   // 4 consecutive tokens
        u16x4 vv;
        #pragma unroll
        for (int t = 0; t < 4; ++t) vv[t] = f2bf(acc[i][j][t] + bv);
        *(u16x4*)&C2[((size_t)(rb >> 5) * 256 + cv) * 32 + (rb & 31)] = vv;
      } else {
        #pragma unroll
        for (int t = 0; t < 4; ++t) {
          const int r = row0 + wr + i*16 + fg*4 + t;
          float v = acc[i][j][t] + bv;
          if (MODE == 1) v = v > 0.f ? v : 0.f;
          C0[(size_t)r * ldc + coff + c] = f2bf(v);
        }
      }
    }
  }
}

template<int MODE, int AF32>
__global__ __launch_bounds__(256) void gemm_bt(
    const void* __restrict__ Ap_, int lda, const u16* __restrict__ Bt,
    const float* __restrict__ bias, u16* __restrict__ C0, int ldc, int coff,
    u16* __restrict__ C2, int vsplit, int N, int K, int gy)
{
  __shared__ u16 As[2 * 128 * 32];
  __shared__ u16 Bs[2 * 128 * 32];
  gemm_body<MODE, AF32>(Ap_, lda, Bt, bias, C0, ldc, coff, C2, vsplit,
                        N, K, gy, gridDim.x, blockIdx.x, As, Bs);
}

// Combined layer-1 projections: blocks [0,2048) = Q-proj (query -> QKc cols
// 0..255), blocks [2048,6144) = K|V-proj (keyval -> QKc cols 256..511 + Vtc).
// Same verified MODE-2/AF32 body; vsplit=1<<30 disables vpart for Q segment.
__global__ __launch_bounds__(256) void gemm_l1(
    const float* __restrict__ query, const float* __restrict__ keyval,
    const u16* __restrict__ WqkvT, const float* __restrict__ bq,
    const float* __restrict__ bkv, u16* __restrict__ QKc,
    u16* __restrict__ Vtc)
{
  __shared__ u16 As[2 * 128 * 32];
  __shared__ u16 Bs[2 * 128 * 32];
  const int o = blockIdx.x;
  if (o < 2048) {
    gemm_body<2, 1>(query, 256, WqkvT, bq, QKc, 512, 0, Vtc, 1 << 30,
                    256, 256, 2, 2048, o, As, Bs);
  } else {
    gemm_body<2, 1>(keyval, 256, WqkvT + 65536, bkv, QKc, 512, 256, Vtc, 256,
                    512, 256, 4, 4096, o - 2048, As, Bs);
  }
}

// ---------------------------------------------------------------------------
// O-proj + bias + residual + LayerNorm fused (full-row tile).
// 128 rows x 256 cols per block, 8 waves (2 row x 4 col of 64x64), BK=32.
// RES_F32: residual read as fp32 (layer 1: raw query) or bf16 (layer 2).
// ---------------------------------------------------------------------------
template<int RES_F32>
__global__ __launch_bounds__(512) void gemm_oln(
    const u16* __restrict__ Ap, int lda, const u16* __restrict__ Bt,
    const float* __restrict__ bias, const void* __restrict__ Res,
    const float* __restrict__ g, const float* __restrict__ be,
    u16* __restrict__ Y, int K)
{
  __shared__ u16 As[2][128 * 32];    // 8 KB x2
  __shared__ u16 Bs[2][256 * 32];    // 16 KB x2
  __shared__ float2 red[128][4];     // 4 KB
  __shared__ float2 stats[128];      // 1 KB
  const int tid  = threadIdx.x;
  const int lane = tid & 63, w = tid >> 6;
  const int nwg = gridDim.x, o = blockIdx.x;
  const int lid = (o & 7) * (nwg >> 3) + (o >> 3);   // XCD chunk
  const int row0 = lid * 128;
  const int wr = (w >> 2) * 64, wc = (w & 3) * 64;
  const int fr = lane & 15, fg = lane >> 4;
  const int sr   = lane >> 2;
  const int sslot = (lane & 3) ^ ((lane >> 2) & 3);

  auto stage = [&](int buf, int k0) {
    gload16((const char*)Ap + ((size_t)(row0 + (w << 4) + sr) * lda + k0) * 2 + sslot*16,
            &As[buf][((w << 4)) * 32]);
    #pragma unroll
    for (int h = 0; h < 2; ++h)
      gload16((const char*)Bt + ((size_t)((w << 5) + h*16 + sr) * K + k0) * 2 + sslot*16,
              &Bs[buf][((w << 5) + h*16) * 32]);
  };

  f32x4 acc[4][4] = {};

  stage(0, 0);
  __syncthreads();
  int cur = 0;
  for (int k0 = 0; k0 < K; k0 += 32) {
    if (k0 + 32 < K) stage(cur ^ 1, k0 + 32);
    bf16x8 af[4], bf[4];
    #pragma unroll
    for (int i = 0; i < 4; ++i) {
      const int r = wr + i*16 + fr;
      af[i] = *(const bf16x8*)&As[cur][r*32 + ((fg ^ (fr & 3)) << 3)];
    }
    #pragma unroll
    for (int j = 0; j < 4; ++j) {
      const int r = wc + j*16 + fr;
      bf[j] = *(const bf16x8*)&Bs[cur][r*32 + ((fg ^ (fr & 3)) << 3)];
    }
    #pragma unroll
    for (int i = 0; i < 4; ++i)
      #pragma unroll
      for (int j = 0; j < 4; ++j)
        acc[i][j] = __builtin_amdgcn_mfma_f32_16x16x32_bf16(af[i], bf[j], acc[i][j], 0, 0, 0);
    __syncthreads();
    cur ^= 1;
  }

  // epilogue: v = acc + bias + residual; row stats; LN; store
  float ps[4][4] = {}, pq[4][4] = {};
  #pragma unroll
  for (int j = 0; j < 4; ++j) {
    const int c = wc + j*16 + fr;
    const float bv = bias[c];
    #pragma unroll
    for (int i = 0; i < 4; ++i) {
      #pragma unroll
      for (int t = 0; t < 4; ++t) {
        const int r = row0 + wr + i*16 + fg*4 + t;
        const float rv = RES_F32 ? ((const float*)Res)[(size_t)r * 256 + c]
                                 : bf2f(((const u16*)Res)[(size_t)r * 256 + c]);
        float v = acc[i][j][t] + bv + rv;
        acc[i][j][t] = v;
        ps[i][t] += v;
        pq[i][t] += v * v;
      }
    }
  }
  #pragma unroll
  for (int d = 1; d < 16; d <<= 1) {
    #pragma unroll
    for (int i = 0; i < 4; ++i)
      #pragma unroll
      for (int t = 0; t < 4; ++t) {
        ps[i][t] += __shfl_xor(ps[i][t], d, 64);
        pq[i][t] += __shfl_xor(pq[i][t], d, 64);
      }
  }
  if (fr == 0) {
    #pragma unroll
    for (int i = 0; i < 4; ++i)
      #pragma unroll
      for (int t = 0; t < 4; ++t)
        red[wr + i*16 + fg*4 + t][w & 3] = make_float2(ps[i][t], pq[i][t]);
  }
  __syncthreads();
  if (tid < 128) {
    float S = 0.f, Q = 0.f;
    #pragma unroll
    for (int ww = 0; ww < 4; ++ww) { float2 p = red[tid][ww]; S += p.x; Q += p.y; }
    const float m = S * (1.f/256.f);
    const float var = Q * (1.f/256.f) - m*m;
    stats[tid] = make_float2(m, rsqrtf(var + 1e-5f));
  }
  __syncthreads();
  #pragma unroll
  for (int i = 0; i < 4; ++i) {
    #pragma unroll
    for (int t = 0; t < 4; ++t) {
      const int rl = wr + i*16 + fg*4 + t;
      const float2 st = stats[rl];
      const size_t r = row0 + rl;
      #pragma unroll
      for (int j = 0; j < 4; ++j) {
        const int c = wc + j*16 + fr;
        Y[r * 256 + c] = f2bf((acc[i][j][t] - st.x) * st.y * g[c] + be[c]);
      }
    }
  }
}

// ---------------------------------------------------------------------------
// Fused FFN v4: Y = LayerNorm( X + relu(X@W1 + bf1)@W2 + bf2 ; g,be ).
// K32 GEMM2 via wave-private LDS H-bounce + T4 counted-vmcnt pipeline:
// 4 weight buffers, depth-2 prefetch, raw s_barrier, s_waitcnt vmcnt(8)
// steady state (never 0; tail peels 4 -> 0). Stage issued BEFORE the
// wait+barrier pair (the fine interleave IS the asset — m196 lesson).
// 256-row blocks, 8 waves x 32 rows (2 row-groups; W frags feed 2 mfma each).
// ---------------------------------------------------------------------------
template<int OUT_F32>
__global__ __launch_bounds__(512, 2) void ffn_fused(
    const u16* __restrict__ X, const u16* __restrict__ W1T,
    const float* __restrict__ b1, const u16* __restrict__ W2T,
    const float* __restrict__ b2, const float* __restrict__ g,
    const float* __restrict__ be, void* __restrict__ Y)
{
  __shared__ u16 W1s[4][32 * 256];   // [h 32][k 256], granule ^= row&7
  __shared__ u16 W2s[4][256 * 32];   // [n 256][k 32], granule ^= (row>>1)&3
  __shared__ u16 Hs[8][32 * 32];     // per-wave [tok 32][h 32], 64B rows
  __shared__ float b1s[1024];
  const int tid = threadIdx.x, lane = tid & 63, w = tid >> 6;
  const int fr = lane & 15, fg = lane >> 4;
  const int row0 = blockIdx.x * 256 + w * 32;
  u16* Hw = &Hs[w][0];
  const int hxor = (fr >> 1) & 3;

  auto stage = [&](int buf, int hb) {
    #pragma unroll
    for (int h = 0; h < 2; ++h) {   // W1 slice [32][256]: 2 rows/wave/issue
      const int r = w*4 + h*2 + (lane >> 5);
      const int sl = (lane & 31) ^ (r & 7);
      gload16((const char*)W1T + ((size_t)((hb << 5) + r) * 256 + sl*8) * 2,
              &W1s[buf][(w*4 + h*2) * 256]);
    }
    #pragma unroll
    for (int h = 0; h < 2; ++h) {   // W2 slice [256][32]: 16 rows/wave/issue
      const int r = w*32 + h*16 + (lane >> 2);
      const int sl = (lane & 3) ^ ((r >> 1) & 3);
      gload16((const char*)W2T + ((size_t)r * 1024 + (hb << 5) + sl*8) * 2,
              &W2s[buf][(w*32 + h*16) * 32]);
    }
  };

  if (tid < 256) {
    f32x4 bv = *(const f32x4*)&b1[tid * 4];
    *(f32x4*)&b1s[tid * 4] = bv;
  }
  bf16x8 af[2][8];
  #pragma unroll
  for (int g2 = 0; g2 < 2; ++g2)
    #pragma unroll
    for (int kf = 0; kf < 8; ++kf)
      af[g2][kf] = *(const bf16x8*)&X[(size_t)(row0 + g2*16 + fr) * 256 + kf*32 + fg*8];
  asm volatile("s_waitcnt vmcnt(0)" ::: "memory");   // af + b1 drained

  f32x4 acc2[2][16] = {};   // out rows g*16+fg*4+t, col nf*16+fr

  auto compute_slice = [&](int hb, int cur) {
    f32x4 acc1[2][2] = {};   // [hf][g]
    #pragma unroll
    for (int kf = 0; kf < 8; ++kf) {
      #pragma unroll
      for (int hf = 0; hf < 2; ++hf) {
        const int n = hf*16 + fr;
        bf16x8 w1f = *(const bf16x8*)&W1s[cur][n*256 + ((((kf << 2) | fg) ^ (n & 7)) << 3)];
        acc1[hf][0] = __builtin_amdgcn_mfma_f32_16x16x32_bf16(w1f, af[0][kf], acc1[hf][0], 0, 0, 0);
        acc1[hf][1] = __builtin_amdgcn_mfma_f32_16x16x32_bf16(w1f, af[1][kf], acc1[hf][1], 0, 0, 0);
      }
    }
    #pragma unroll
    for (int g2 = 0; g2 < 2; ++g2) {
      #pragma unroll
      for (int hf = 0; hf < 2; ++hf) {
        const int h0 = hf*16 + fg*4;
        f32x4 b4 = *(const f32x4*)&b1s[(hb << 5) + h0];
        u16x4 hv;
        #pragma unroll
        for (int t = 0; t < 4; ++t) {
          float v = acc1[hf][g2][t] + b4[t];
          hv[t] = f2bf(v > 0.f ? v : 0.f);
        }
        const int tok = g2*16 + fr;
        *(u16x4*)((char*)Hw + tok*64 + ((((hf << 1) | (fg >> 1)) ^ hxor) << 4)
                                     + ((fg & 1) << 3)) = hv;
      }
    }
    asm volatile("s_waitcnt lgkmcnt(0)" ::: "memory");   // cross-lane H hazard
    __builtin_amdgcn_sched_barrier(0);                   // rule #18

    bf16x8 hf2[2];
    #pragma unroll
    for (int g2 = 0; g2 < 2; ++g2) {
      const int tok = g2*16 + fr;
      hf2[g2] = *(const bf16x8*)((char*)Hw + tok*64 + ((fg ^ hxor) << 4));
    }
    #pragma unroll
    for (int nf = 0; nf < 16; ++nf) {
      const int n = nf*16 + fr;
      bf16x8 w2f = *(const bf16x8*)&W2s[cur][n*32 + ((fg ^ ((n >> 1) & 3)) << 3)];
      acc2[0][nf] = __builtin_amdgcn_mfma_f32_16x16x32_bf16(hf2[0], w2f, acc2[0][nf], 0, 0, 0);
      acc2[1][nf] = __builtin_amdgcn_mfma_f32_16x16x32_bf16(hf2[1], w2f, acc2[1][nf], 0, 0, 0);
    }
  };

  stage(0, 0);
  stage(1, 1);
  for (int hb = 0; hb < 30; ++hb) {
    stage((hb + 2) & 3, hb + 2);                       // depth-2 prefetch
    asm volatile("s_waitcnt vmcnt(8)" ::: "memory");   // cur-slice loads done
    __builtin_amdgcn_s_barrier();
    __builtin_amdgcn_sched_barrier(0);
    compute_slice(hb, hb & 3);
  }
  asm volatile("s_waitcnt vmcnt(4)" ::: "memory");     // tail: slice 30
  __builtin_amdgcn_s_barrier();
  __builtin_amdgcn_sched_barrier(0);
  compute_slice(30, 30 & 3);
  asm volatile("s_waitcnt vmcnt(0)" ::: "memory");     // tail: slice 31
  __builtin_amdgcn_s_barrier();
  __builtin_amdgcn_sched_barrier(0);
  compute_slice(31, 31 & 3);

  // epilogue: bias2 + residual + LayerNorm, per row-group
  #pragma unroll
  for (int g2 = 0; g2 < 2; ++g2) {
    const int rbase = row0 + g2*16 + fg*4;
    float s1[4] = {}, sq[4] = {};
    #pragma unroll
    for (int nf = 0; nf < 16; ++nf) {
      const int c = nf*16 + fr;
      const float b = b2[c];
      #pragma unroll
      for (int t = 0; t < 4; ++t) {
        float v = acc2[g2][nf][t] + b + bf2f(X[(size_t)(rbase + t) * 256 + c]);
        acc2[g2][nf][t] = v;
        s1[t] += v; sq[t] += v * v;
      }
    }
    #pragma unroll
    for (int d = 1; d < 16; d <<= 1) {
      #pragma unroll
      for (int t = 0; t < 4; ++t) {
        s1[t] += __shfl_xor(s1[t], d, 64);
        sq[t] += __shfl_xor(sq[t], d, 64);
      }
    }
    float mean[4], rstd[4];
    #pragma unroll
    for (int t = 0; t < 4; ++t) {
      mean[t] = s1[t] * (1.f/256.f);
      const float var = sq[t] * (1.f/256.f) - mean[t]*mean[t];
      rstd[t] = rsqrtf(var + 1e-5f);
    }
    #pragma unroll
    for (int nf = 0; nf < 16; ++nf) {
      const int c = nf*16 + fr;
      const float gc = g[c], bc = be[c];
      #pragma unroll
      for (int t = 0; t < 4; ++t) {
        const float y = (acc2[g2][nf][t] - mean[t]) * rstd[t] * gc + bc;
        if (OUT_F32) ((float*)Y)[(size_t)(rbase + t) * 256 + c] = y;
        else         ((u16*)Y)[(size_t)(rbase + t) * 256 + c] = f2bf(y);
      }
    }
  }
}

// ---------------------------------------------------------------------------
// MFMA windowed attention. One wave per window (4 waves/block, no block
// barriers). Per head: S=QK^T via 4 mfma, softmax in C-layout (shfl_xor over
// 16-lane fr group, normalization deferred), P -> wave-private LDS -> A-frags,
// O=PV via 4 mfma with B-frags from window-transposed Vt[win][dim][key].
// O may alias Q (per head, Q cols read before O cols stored).
// ---------------------------------------------------------------------------
__global__ __launch_bounds__(256) void attn_mfma(
    const u16* Q, int sq, const u16* __restrict__ K, int sk,
    const u16* __restrict__ Vt, u16* O, int so)
{
  __shared__ u16 P[4][32 * 40];
  const int tid = threadIdx.x, lane = tid & 63, w = tid >> 6;
  const int win = blockIdx.x * 4 + w;
  const size_t q0 = (size_t)win * 32;
  const int fr = lane & 15, fg = lane >> 4;
  u16* Pw = &P[w][0];
  const float scale = 0.17677669529663687f;   // 1/sqrt(32)

  for (int h = 0; h < 8; ++h) {
    const int co = h * 32;
    bf16x8 qa[2], kb[2];
    #pragma unroll
    for (int i = 0; i < 2; ++i)
      qa[i] = *(const bf16x8*)&Q[(q0 + i*16 + fr) * sq + co + fg*8];
    #pragma unroll
    for (int j = 0; j < 2; ++j)
      kb[j] = *(const bf16x8*)&K[(q0 + j*16 + fr) * sk + co + fg*8];
    f32x4 s[2][2] = {};
    #pragma unroll
    for (int i = 0; i < 2; ++i)
      #pragma unroll
      for (int j = 0; j < 2; ++j)
        s[i][j] = __builtin_amdgcn_mfma_f32_16x16x32_bf16(qa[i], kb[j], s[i][j], 0, 0, 0);

    float inv[2][4];
    #pragma unroll
    for (int i = 0; i < 2; ++i) {
      #pragma unroll
      for (int t = 0; t < 4; ++t) {
        float a0 = s[i][0][t] * scale, a1 = s[i][1][t] * scale;
        float mx = fmaxf(a0, a1);
        #pragma unroll
        for (int d = 1; d < 16; d <<= 1) mx = fmaxf(mx, __shfl_xor(mx, d, 64));
        const float p0 = __expf(a0 - mx), p1 = __expf(a1 - mx);
        float sm = p0 + p1;
        #pragma unroll
        for (int d = 1; d < 16; d <<= 1) sm += __shfl_xor(sm, d, 64);
        inv[i][t] = 1.f / sm;
        const int q = i*16 + fg*4 + t;
        Pw[q*40 + fr]      = f2bf(p0);
        Pw[q*40 + 16 + fr] = f2bf(p1);
      }
    }

    bf16x8 pa[2], vb[2];
    #pragma unroll
    for (int i = 0; i < 2; ++i)
      pa[i] = *(const bf16x8*)&Pw[(i*16 + fr)*40 + fg*8];
    #pragma unroll
    for (int j = 0; j < 2; ++j)
      vb[j] = *(const bf16x8*)&Vt[(size_t)win*8192 + (co + j*16 + fr)*32 + fg*8];
    f32x4 oacc[2][2] = {};
    #pragma unroll
    for (int i = 0; i < 2; ++i)
      #pragma unroll
      for (int j = 0; j < 2; ++j)
        oacc[i][j] = __builtin_amdgcn_mfma_f32_16x16x32_bf16(pa[i], vb[j], oacc[i][j], 0, 0, 0);

    #pragma unroll
    for (int i = 0; i < 2; ++i)
      #pragma unroll
      for (int j = 0; j < 2; ++j)
        #pragma unroll
        for (int t = 0; t < 4; ++t)
          O[(q0 + i*16 + fg*4 + t) * so + co + j*16 + fr] =
              f2bf(oacc[i][j][t] * inv[i][t]);
  }
}

// ---------------------------------------------------------------------------
// All weight prep in ONE launch. Blocks:
//  [0,256) Wq, [256,512) Wk, [512,768) Wv, [768,1024) Wo  (each 256x256)
//  [1024,2048) W1 (256x1024), [2048,3072) W2 (1024x256)
//  [3072,3075) bias concat bq|bk|bv
// ---------------------------------------------------------------------------
__global__ __launch_bounds__(256) void wprep_all(
    const float* __restrict__ Wq, const float* __restrict__ Wk,
    const float* __restrict__ Wv, const float* __restrict__ Wo,
    const float* __restrict__ W1, const float* __restrict__ W2,
    const float* __restrict__ bq, const float* __restrict__ bk,
    const float* __restrict__ bv,
    u16* __restrict__ WqkvT, u16* __restrict__ WoT,
    u16* __restrict__ W1T, u16* __restrict__ W2T, float* __restrict__ bqkv)
{
  const int b = blockIdx.x, t = threadIdx.x;
  if (b < 1024) {           // 256x256 transposes
    const int which = b >> 8, idx = ((b & 255) << 8) + t;
    const float* W = which == 0 ? Wq : which == 1 ? Wk : which == 2 ? Wv : Wo;
    u16* Wt = which == 3 ? WoT : WqkvT + which * 65536;
    const int k = idx >> 8, n = idx & 255;
    Wt[n * 256 + k] = f2bf(W[idx]);
  } else if (b < 2048) {    // W1 [256][1024] -> W1T [1024][256]
    const int idx = ((b - 1024) << 8) + t;
    const int k = idx >> 10, n = idx & 1023;
    W1T[n * 256 + k] = f2bf(W1[idx]);
  } else if (b < 3072) {    // W2 [1024][256] -> W2T [256][1024]
    const int idx = ((b - 2048) << 8) + t;
    const int k = idx >> 8, n = idx & 255;
    W2T[n * 1024 + k] = f2bf(W2[idx]);
  } else {                  // bias concat
    const int i = ((b - 3072) << 8) + t;
    bqkv[i] = i < 256 ? bq[i] : (i < 512 ? bk[i - 256] : bv[i - 512]);
  }
}

// ---------------------------------------------------------------------------
extern "C" void kernel_launch(void* const* d_in, const int* in_sizes, int n_in,
                              void* d_out, int out_size, void* d_ws, size_t ws_size,
                              hipStream_t stream)
{
  const float* query  = (const float*)d_in[0];
  const float* keyval = (const float*)d_in[1];
  const float* Wq = (const float*)d_in[2];  const float* bq  = (const float*)d_in[3];
  const float* Wk = (const float*)d_in[4];  const float* bk  = (const float*)d_in[5];
  const float* Wv = (const float*)d_in[6];  const float* bv  = (const float*)d_in[7];
  const float* Wo = (const float*)d_in[8];  const float* bo  = (const float*)d_in[9];
  const float* g1 = (const float*)d_in[10]; const float* be1 = (const float*)d_in[11];
  const float* W1 = (const float*)d_in[12]; const float* bf1 = (const float*)d_in[13];
  const float* W2 = (const float*)d_in[14]; const float* bf2 = (const float*)d_in[15];
  const float* g2 = (const float*)d_in[16]; const float* be2 = (const float*)d_in[17];

  const int M = 131072;      // B*L token rows
  char* ws = (char*)d_ws;
  // Workspace (<=450 MiB of 512 MiB d_ws):
  //   [0,64)     xcur bf16 [M][256]   (layer-2 input, written by L1 ffn)
  //   [64,128)   x1   bf16 [M][256]
  //   [256,384)  QKc  bf16 [M][512]   (Q | K cols; attn O in place over Q)
  //   [384,448)  Vtc  bf16 [4096 win][256][32]  (window-transposed V)
  //   [448,..)   bf16 weights + fused qkv bias
  u16*  xcur = (u16*)ws;
  u16*  x1   = (u16*)(ws + (64ull  << 20));
  u16*  QKc  = (u16*)(ws + (256ull << 20));
  u16*  Vtc  = (u16*)(ws + (384ull << 20));
  u16*  WqkvT = (u16*)(ws + (448ull << 20));   // [768][256] = Wq|Wk|Wv rows
  u16*  WoT   = WqkvT + 196608;                // [256][256]
  u16*  W1T   = WoT   + 65536;                 // [1024][256]
  u16*  W2T   = W1T   + 262144;                // [256][1024]
  float* bqkv = (float*)(W2T + 262144);        // [768]
  float* bkv  = bqkv + 256;                    // [512] = bk|bv

  wprep_all<<<3075, 256, 0, stream>>>(Wq, Wk, Wv, Wo, W1, W2, bq, bk, bv,
                                      WqkvT, WoT, W1T, W2T, bqkv);

  // NOTE: jnp.roll(x, -16, axis=1) permutes whole windows; the encoder layer is
  // window-local and position-independent, so roll + layer + unroll == layer.
  // Both rolls are elided (bit-exact equivalence).

  // ---- layer 1: A inputs are raw fp32 (converted during GEMM staging) ----
  gemm_l1<<<6144, 256, 0, stream>>>(query, keyval, WqkvT, bq, bkv, QKc, Vtc);
  attn_mfma<<<1024, 256, 0, stream>>>(QKc, 512, QKc + 256, 512, Vtc, QKc, 512);
  gemm_oln<1><<<1024, 512, 0, stream>>>(
      QKc, 512, WoT, bo, query, g1, be1, x1, 256);        // residual = fp32 query
  ffn_fused<0><<<512, 512, 0, stream>>>(
      x1, W1T, bf1, W2T, bf2, g2, be2, xcur);

  // ---- layer 2: q = kv = xcur (bf16) ----
  gemm_bt<2,0><<<6144, 256, 0, stream>>>(
      xcur, 256, WqkvT, bqkv, QKc, 512, 0, Vtc, 512, 768, 256, 6);
  attn_mfma<<<1024, 256, 0, stream>>>(QKc, 512, QKc + 256, 512, Vtc, QKc, 512);
  gemm_oln<0><<<1024, 512, 0, stream>>>(
      QKc, 512, WoT, bo, xcur, g1, be1, x1, 256);         // residual = bf16 xcur
  ffn_fused<1><<<512, 512, 0, stream>>>(
      x1, W1T, bf1, W2T, bf2, g2, be2, d_out);
}

// Round 20
// 881.194 us; speedup vs baseline: 1.0635x; 1.0010x over previous
//
#include <hip/hip_runtime.h>
#include <cstdint>
#include <cstddef>

typedef unsigned short u16;
typedef __bf16 bf16x8 __attribute__((ext_vector_type(8)));
typedef float f32x4 __attribute__((ext_vector_type(4)));
typedef unsigned short u16x8 __attribute__((ext_vector_type(8)));
typedef unsigned short u16x4 __attribute__((ext_vector_type(4)));

__device__ __forceinline__ u16 f2bf(float f) {
  union { float f; unsigned u; } x; x.f = f;
  unsigned r = x.u + 0x7fffu + ((x.u >> 16) & 1u);   // RNE
  return (u16)(r >> 16);
}
__device__ __forceinline__ float bf2f(u16 u) {
  union { unsigned u; float f; } x; x.u = ((unsigned)u) << 16;
  return x.f;
}
// async global->LDS, 16B/lane; LDS dest = wave-uniform base + lane*16 (linear)
__device__ __forceinline__ void gload16(const void* g, void* l) {
  __builtin_amdgcn_global_load_lds(
      (const __attribute__((address_space(1))) unsigned int*)g,
      (__attribute__((address_space(3))) unsigned int*)l, 16, 0, 0);
}

// ---------------------------------------------------------------------------
// bf16 GEMM (layer 2): C = A[.][K](lda) @ Bt^T + bias. 128x128 tile, BK=32,
// 4 waves, 2-phase double-buffered, slot swizzle slot^(row&3) both sides.
// MODE 2: split route: col<vsplit natural into C0 (+coff);
//         col>=vsplit window-transposed into C2[win][c-vsplit][tok&31]
// ---------------------------------------------------------------------------
template<int MODE>
__global__ __launch_bounds__(256) void gemm_bt(
    const u16* __restrict__ Ab, int lda, const u16* __restrict__ Bt,
    const float* __restrict__ bias, u16* __restrict__ C0, int ldc, int coff,
    u16* __restrict__ C2, int vsplit, int N, int K, int gy)
{
  __shared__ u16 As[2 * 128 * 32];
  __shared__ u16 Bs[2 * 128 * 32];
  const int tid  = threadIdx.x;
  const int lane = tid & 63, w = tid >> 6;
  const int nwg = gridDim.x, o = blockIdx.x;
  const int lid = (o & 7) * (nwg >> 3) + (o >> 3);   // contiguous lid -> same XCD
  const int by = lid % gy, bx = lid / gy;
  const int row0 = bx * 128, col0 = by * 128;
  const int wr = (w >> 1) * 64, wc = (w & 1) * 64;
  const int fr = lane & 15, fg = lane >> 4;
  const int srow  = (w << 5) + (lane >> 2);
  const int sslot = (lane & 3) ^ ((lane >> 2) & 3);
  const int AB = 128 * 32;

  auto stageB = [&](int buf, int k0) {
    #pragma unroll
    for (int h = 0; h < 2; ++h)
      gload16((const char*)Bt + ((size_t)(col0 + srow + h*16) * K + k0) * 2 + sslot*16,
              &Bs[buf*AB + ((w << 5) + h*16) * 32]);
  };
  auto stageA16 = [&](int buf, int k0) {
    #pragma unroll
    for (int h = 0; h < 2; ++h)
      gload16((const char*)Ab + ((size_t)(row0 + srow + h*16) * lda + k0) * 2 + sslot*16,
              &As[buf*AB + ((w << 5) + h*16) * 32]);
  };

  f32x4 acc[4][4] = {};

  stageA16(0, 0); stageB(0, 0);
  __syncthreads();
  int cur = 0;
  for (int k0 = 0; k0 < K; k0 += 32) {
    if (k0 + 32 < K) { stageA16(cur ^ 1, k0 + 32); stageB(cur ^ 1, k0 + 32); }
    bf16x8 af[4], bf[4];
    #pragma unroll
    for (int i = 0; i < 4; ++i) {
      const int r = wr + i*16 + fr;
      af[i] = *(const bf16x8*)&As[cur*AB + r*32 + ((fg ^ (fr & 3)) << 3)];
    }
    #pragma unroll
    for (int j = 0; j < 4; ++j) {
      const int r = wc + j*16 + fr;
      bf[j] = *(const bf16x8*)&Bs[cur*AB + r*32 + ((fg ^ (fr & 3)) << 3)];
    }
    #pragma unroll
    for (int i = 0; i < 4; ++i)
      #pragma unroll
      for (int j = 0; j < 4; ++j)
        acc[i][j] = __builtin_amdgcn_mfma_f32_16x16x32_bf16(af[i], bf[j], acc[i][j], 0, 0, 0);
    __syncthreads();
    cur ^= 1;
  }

  const int vpart = (MODE == 2 && col0 >= vsplit);
  #pragma unroll
  for (int j = 0; j < 4; ++j) {
    const int c  = col0 + wc + j*16 + fr;
    const float bv = bias[c];
    #pragma unroll
    for (int i = 0; i < 4; ++i) {
      if (vpart) {
        const int cv = c - vsplit;
        const int rb = row0 + wr + i*16 + fg*4;
        u16x4 vv;
        #pragma unroll
        for (int t = 0; t < 4; ++t) vv[t] = f2bf(acc[i][j][t] + bv);
        *(u16x4*)&C2[((size_t)(rb >> 5) * 256 + cv) * 32 + (rb & 31)] = vv;
      } else {
        #pragma unroll
        for (int t = 0; t < 4; ++t) {
          const int r = row0 + wr + i*16 + fg*4 + t;
          C0[(size_t)r * ldc + coff + c] = f2bf(acc[i][j][t] + bv);
        }
      }
    }
  }
}

// ---------------------------------------------------------------------------
// fp32-A GEMM with depth-2 counted-vmcnt pipeline (layer-1 projections).
// Per iter j: [load A(j+2)->regs][vmcnt(6): A(j+1)+B(j) done][ds_write A(j+1)]
// [lgkmcnt(0)][s_barrier][stage B(j+2) via gload_lds][MFMA on tile j].
// Buffers: As[3], Bs[3] (reuse barrier-separated, ledger in notes). Waits are
// per-wave and precede the barrier -> cross-wave visibility guaranteed.
// Tail peels vmcnt 6 -> 2 -> 0. Epilogue: MODE-2 split route.
// ---------------------------------------------------------------------------
__device__ __forceinline__ void gemm_f32_pipe(
    const float* __restrict__ Af, int lda, const u16* __restrict__ Bt,
    const float* __restrict__ bias, u16* __restrict__ C0, int ldc, int coff,
    u16* __restrict__ C2, int vsplit, int N, int K, int gy, int nwg, int o,
    u16* As, u16* Bs)   // each 3*128*32 u16
{
  const int tid  = threadIdx.x;
  const int lane = tid & 63, w = tid >> 6;
  const int lid = (o & 7) * (nwg >> 3) + (o >> 3);
  const int by = lid % gy, bx = lid / gy;
  const int row0 = bx * 128, col0 = by * 128;
  const int wr = (w >> 1) * 64, wc = (w & 1) * 64;
  const int fr = lane & 15, fg = lane >> 4;
  const int srow  = (w << 5) + (lane >> 2);
  const int sslot = (lane & 3) ^ ((lane >> 2) & 3);
  const int AB = 128 * 32;
  const int NT = K >> 5;

  auto stageB = [&](int buf, int k0) {
    #pragma unroll
    for (int h = 0; h < 2; ++h)
      gload16((const char*)Bt + ((size_t)(col0 + srow + h*16) * K + k0) * 2 + sslot*16,
              &Bs[buf*AB + ((w << 5) + h*16) * 32]);
  };
  f32x4 pre[2][2][2];   // [set][p][half]
  auto loadA32 = [&](int set, int k0) {
    #pragma unroll
    for (int p = 0; p < 2; ++p) {
      const int sidx = tid + p*256, rr = sidx >> 2, sl = sidx & 3;
      const float* src = &Af[(size_t)(row0 + rr) * lda + k0 + sl*8];
      pre[set][p][0] = *(const f32x4*)src;
      pre[set][p][1] = *(const f32x4*)(src + 4);
    }
  };
  auto writeA32 = [&](int set, int buf) {
    #pragma unroll
    for (int p = 0; p < 2; ++p) {
      const int sidx = tid + p*256, rr = sidx >> 2, sl = sidx & 3;
      u16x8 ov = { f2bf(pre[set][p][0][0]), f2bf(pre[set][p][0][1]),
                   f2bf(pre[set][p][0][2]), f2bf(pre[set][p][0][3]),
                   f2bf(pre[set][p][1][0]), f2bf(pre[set][p][1][1]),
                   f2bf(pre[set][p][1][2]), f2bf(pre[set][p][1][3]) };
      *(u16x8*)&As[buf*AB + rr*32 + ((sl ^ (rr & 3)) << 3)] = ov;
    }
  };

  f32x4 acc[4][4] = {};

  // prologue: A0,A1 in flight; B0 staged; A0 -> As[0]; B1 staged post-barrier
  loadA32(0, 0);
  loadA32(1, 32);
  stageB(0, 0);
  asm volatile("s_waitcnt vmcnt(6)" ::: "memory");     // A0 done
  writeA32(0, 0);
  asm volatile("s_waitcnt lgkmcnt(0)" ::: "memory");
  __builtin_amdgcn_s_barrier();
  __builtin_amdgcn_sched_barrier(0);
  stageB(1, 32);

  for (int j = 0; j < NT; ++j) {
    if (j + 2 < NT) loadA32(j & 1, (j + 2) << 5);      // A(j+2) -> set j%2
    if (j + 2 < NT)      asm volatile("s_waitcnt vmcnt(6)" ::: "memory");
    else if (j + 1 < NT) asm volatile("s_waitcnt vmcnt(2)" ::: "memory");
    else                 asm volatile("s_waitcnt vmcnt(0)" ::: "memory");
    // ^ proves: this wave's A(j+1) loaded (for write) and B(j) landed (for MFMA)
    if (j + 1 < NT) {
      writeA32((j + 1) & 1, (j + 1) % 3);
      asm volatile("s_waitcnt lgkmcnt(0)" ::: "memory");
    }
    __builtin_amdgcn_s_barrier();
    __builtin_amdgcn_sched_barrier(0);
    if (j + 2 < NT) stageB((j + 2) % 3, (j + 2) << 5); // post-barrier: 3 bufs safe
    const int cb = j % 3;
    bf16x8 af[4], bf[4];
    #pragma unroll
    for (int i = 0; i < 4; ++i) {
      const int r = wr + i*16 + fr;
      af[i] = *(const bf16x8*)&As[cb*AB + r*32 + ((fg ^ (fr & 3)) << 3)];
    }
    #pragma unroll
    for (int j2 = 0; j2 < 4; ++j2) {
      const int r = wc + j2*16 + fr;
      bf[j2] = *(const bf16x8*)&Bs[cb*AB + r*32 + ((fg ^ (fr & 3)) << 3)];
    }
    #pragma unroll
    for (int i = 0; i < 4; ++i)
      #pragma unroll
      for (int j2 = 0; j2 < 4; ++j2)
        acc[i][j2] = __builtin_amdgcn_mfma_f32_16x16x32_bf16(af[i], bf[j2], acc[i][j2], 0, 0, 0);
  }

  // epilogue: D[row=fg*4+t][col=fr] per 16x16 fragment (m89-verified mapping)
  const int vpart = (col0 >= vsplit);
  #pragma unroll
  for (int j = 0; j < 4; ++j) {
    const int c  = col0 + wc + j*16 + fr;
    const float bv = bias[c];
    #pragma unroll
    for (int i = 0; i < 4; ++i) {
      if (vpart) {
        const int cv = c - vsplit;
        const int rb = row0 + wr + i*16 + fg*4;
        u16x4 vv;
        #pragma unroll
        for (int t = 0; t < 4; ++t) vv[t] = f2bf(acc[i][j][t] + bv);
        *(u16x4*)&C2[((size_t)(rb >> 5) * 256 + cv) * 32 + (rb & 31)] = vv;
      } else {
        #pragma unroll
        for (int t = 0; t < 4; ++t) {
          const int r = row0 + wr + i*16 + fg*4 + t;
          C0[(size_t)r * ldc + coff + c] = f2bf(acc[i][j][t] + bv);
        }
      }
    }
  }
}

// Combined layer-1 projections: blocks [0,2048) = Q-proj (query -> QKc cols
// 0..255), blocks [2048,6144) = K|V-proj (keyval -> QKc cols 256..511 + Vtc).
__global__ __launch_bounds__(256) void gemm_l1(
    const float* __restrict__ query, const float* __restrict__ keyval,
    const u16* __restrict__ WqkvT, const float* __restrict__ bq,
    const float* __restrict__ bkv, u16* __restrict__ QKc,
    u16* __restrict__ Vtc)
{
  __shared__ u16 As[3 * 128 * 32];
  __shared__ u16 Bs[3 * 128 * 32];
  const int o = blockIdx.x;
  if (o < 2048) {
    gemm_f32_pipe(query, 256, WqkvT, bq, QKc, 512, 0, Vtc, 1 << 30,
                  256, 256, 2, 2048, o, As, Bs);
  } else {
    gemm_f32_pipe(keyval, 256, WqkvT + 65536, bkv, QKc, 512, 256, Vtc, 256,
                  512, 256, 4, 4096, o - 2048, As, Bs);
  }
}

// ---------------------------------------------------------------------------
// O-proj + bias + residual + LayerNorm fused (full-row tile).
// 128 rows x 256 cols per block, 8 waves (2 row x 4 col of 64x64), BK=32.
// RES_F32: residual read as fp32 (layer 1: raw query) or bf16 (layer 2).
// ---------------------------------------------------------------------------
template<int RES_F32>
__global__ __launch_bounds__(512) void gemm_oln(
    const u16* __restrict__ Ap, int lda, const u16* __restrict__ Bt,
    const float* __restrict__ bias, const void* __restrict__ Res,
    const float* __restrict__ g, const float* __restrict__ be,
    u16* __restrict__ Y, int K)
{
  __shared__ u16 As[2][128 * 32];
  __shared__ u16 Bs[2][256 * 32];
  __shared__ float2 red[128][4];
  __shared__ float2 stats[128];
  const int tid  = threadIdx.x;
  const int lane = tid & 63, w = tid >> 6;
  const int nwg = gridDim.x, o = blockIdx.x;
  const int lid = (o & 7) * (nwg >> 3) + (o >> 3);
  const int row0 = lid * 128;
  const int wr = (w >> 2) * 64, wc = (w & 3) * 64;
  const int fr = lane & 15, fg = lane >> 4;
  const int sr   = lane >> 2;
  const int sslot = (lane & 3) ^ ((lane >> 2) & 3);

  auto stage = [&](int buf, int k0) {
    gload16((const char*)Ap + ((size_t)(row0 + (w << 4) + sr) * lda + k0) * 2 + sslot*16,
            &As[buf][((w << 4)) * 32]);
    #pragma unroll
    for (int h = 0; h < 2; ++h)
      gload16((const char*)Bt + ((size_t)((w << 5) + h*16 + sr) * K + k0) * 2 + sslot*16,
              &Bs[buf][((w << 5) + h*16) * 32]);
  };

  f32x4 acc[4][4] = {};

  stage(0, 0);
  __syncthreads();
  int cur = 0;
  for (int k0 = 0; k0 < K; k0 += 32) {
    if (k0 + 32 < K) stage(cur ^ 1, k0 + 32);
    bf16x8 af[4], bf[4];
    #pragma unroll
    for (int i = 0; i < 4; ++i) {
      const int r = wr + i*16 + fr;
      af[i] = *(const bf16x8*)&As[cur][r*32 + ((fg ^ (fr & 3)) << 3)];
    }
    #pragma unroll
    for (int j = 0; j < 4; ++j) {
      const int r = wc + j*16 + fr;
      bf[j] = *(const bf16x8*)&Bs[cur][r*32 + ((fg ^ (fr & 3)) << 3)];
    }
    #pragma unroll
    for (int i = 0; i < 4; ++i)
      #pragma unroll
      for (int j = 0; j < 4; ++j)
        acc[i][j] = __builtin_amdgcn_mfma_f32_16x16x32_bf16(af[i], bf[j], acc[i][j], 0, 0, 0);
    __syncthreads();
    cur ^= 1;
  }

  float ps[4][4] = {}, pq[4][4] = {};
  #pragma unroll
  for (int j = 0; j < 4; ++j) {
    const int c = wc + j*16 + fr;
    const float bv = bias[c];
    #pragma unroll
    for (int i = 0; i < 4; ++i) {
      #pragma unroll
      for (int t = 0; t < 4; ++t) {
        const int r = row0 + wr + i*16 + fg*4 + t;
        const float rv = RES_F32 ? ((const float*)Res)[(size_t)r * 256 + c]
                                 : bf2f(((const u16*)Res)[(size_t)r * 256 + c]);
        float v = acc[i][j][t] + bv + rv;
        acc[i][j][t] = v;
        ps[i][t] += v;
        pq[i][t] += v * v;
      }
    }
  }
  #pragma unroll
  for (int d = 1; d < 16; d <<= 1) {
    #pragma unroll
    for (int i = 0; i < 4; ++i)
      #pragma unroll
      for (int t = 0; t < 4; ++t) {
        ps[i][t] += __shfl_xor(ps[i][t], d, 64);
        pq[i][t] += __shfl_xor(pq[i][t], d, 64);
      }
  }
  if (fr == 0) {
    #pragma unroll
    for (int i = 0; i < 4; ++i)
      #pragma unroll
      for (int t = 0; t < 4; ++t)
        red[wr + i*16 + fg*4 + t][w & 3] = make_float2(ps[i][t], pq[i][t]);
  }
  __syncthreads();
  if (tid < 128) {
    float S = 0.f, Q = 0.f;
    #pragma unroll
    for (int ww = 0; ww < 4; ++ww) { float2 p = red[tid][ww]; S += p.x; Q += p.y; }
    const float m = S * (1.f/256.f);
    const float var = Q * (1.f/256.f) - m*m;
    stats[tid] = make_float2(m, rsqrtf(var + 1e-5f));
  }
  __syncthreads();
  #pragma unroll
  for (int i = 0; i < 4; ++i) {
    #pragma unroll
    for (int t = 0; t < 4; ++t) {
      const int rl = wr + i*16 + fg*4 + t;
      const float2 st = stats[rl];
      const size_t r = row0 + rl;
      #pragma unroll
      for (int j = 0; j < 4; ++j) {
        const int c = wc + j*16 + fr;
        Y[r * 256 + c] = f2bf((acc[i][j][t] - st.x) * st.y * g[c] + be[c]);
      }
    }
  }
}

// ---------------------------------------------------------------------------
// Fused FFN v4: Y = LayerNorm( X + relu(X@W1 + bf1)@W2 + bf2 ; g,be ).
// K32 GEMM2 via wave-private LDS H-bounce + T4 counted-vmcnt pipeline.
// ---------------------------------------------------------------------------
template<int OUT_F32>
__global__ __launch_bounds__(512, 2) void ffn_fused(
    const u16* __restrict__ X, const u16* __restrict__ W1T,
    const float* __restrict__ b1, const u16* __restrict__ W2T,
    const float* __restrict__ b2, const float* __restrict__ g,
    const float* __restrict__ be, void* __restrict__ Y)
{
  __shared__ u16 W1s[4][32 * 256];
  __shared__ u16 W2s[4][256 * 32];
  __shared__ u16 Hs[8][32 * 32];
  __shared__ float b1s[1024];
  const int tid = threadIdx.x, lane = tid & 63, w = tid >> 6;
  const int fr = lane & 15, fg = lane >> 4;
  const int row0 = blockIdx.x * 256 + w * 32;
  u16* Hw = &Hs[w][0];
  const int hxor = (fr >> 1) & 3;

  auto stage = [&](int buf, int hb) {
    #pragma unroll
    for (int h = 0; h < 2; ++h) {
      const int r = w*4 + h*2 + (lane >> 5);
      const int sl = (lane & 31) ^ (r & 7);
      gload16((const char*)W1T + ((size_t)((hb << 5) + r) * 256 + sl*8) * 2,
              &W1s[buf][(w*4 + h*2) * 256]);
    }
    #pragma unroll
    for (int h = 0; h < 2; ++h) {
      const int r = w*32 + h*16 + (lane >> 2);
      const int sl = (lane & 3) ^ ((r >> 1) & 3);
      gload16((const char*)W2T + ((size_t)r * 1024 + (hb << 5) + sl*8) * 2,
              &W2s[buf][(w*32 + h*16) * 32]);
    }
  };

  if (tid < 256) {
    f32x4 bv = *(const f32x4*)&b1[tid * 4];
    *(f32x4*)&b1s[tid * 4] = bv;
  }
  bf16x8 af[2][8];
  #pragma unroll
  for (int g2 = 0; g2 < 2; ++g2)
    #pragma unroll
    for (int kf = 0; kf < 8; ++kf)
      af[g2][kf] = *(const bf16x8*)&X[(size_t)(row0 + g2*16 + fr) * 256 + kf*32 + fg*8];
  asm volatile("s_waitcnt vmcnt(0)" ::: "memory");

  f32x4 acc2[2][16] = {};

  auto compute_slice = [&](int hb, int cur) {
    f32x4 acc1[2][2] = {};
    #pragma unroll
    for (int kf = 0; kf < 8; ++kf) {
      #pragma unroll
      for (int hf = 0; hf < 2; ++hf) {
        const int n = hf*16 + fr;
        bf16x8 w1f = *(const bf16x8*)&W1s[cur][n*256 + ((((kf << 2) | fg) ^ (n & 7)) << 3)];
        acc1[hf][0] = __builtin_amdgcn_mfma_f32_16x16x32_bf16(w1f, af[0][kf], acc1[hf][0], 0, 0, 0);
        acc1[hf][1] = __builtin_amdgcn_mfma_f32_16x16x32_bf16(w1f, af[1][kf], acc1[hf][1], 0, 0, 0);
      }
    }
    #pragma unroll
    for (int g2 = 0; g2 < 2; ++g2) {
      #pragma unroll
      for (int hf = 0; hf < 2; ++hf) {
        const int h0 = hf*16 + fg*4;
        f32x4 b4 = *(const f32x4*)&b1s[(hb << 5) + h0];
        u16x4 hv;
        #pragma unroll
        for (int t = 0; t < 4; ++t) {
          float v = acc1[hf][g2][t] + b4[t];
          hv[t] = f2bf(v > 0.f ? v : 0.f);
        }
        const int tok = g2*16 + fr;
        *(u16x4*)((char*)Hw + tok*64 + ((((hf << 1) | (fg >> 1)) ^ hxor) << 4)
                                     + ((fg & 1) << 3)) = hv;
      }
    }
    asm volatile("s_waitcnt lgkmcnt(0)" ::: "memory");
    __builtin_amdgcn_sched_barrier(0);

    bf16x8 hf2[2];
    #pragma unroll
    for (int g2 = 0; g2 < 2; ++g2) {
      const int tok = g2*16 + fr;
      hf2[g2] = *(const bf16x8*)((char*)Hw + tok*64 + ((fg ^ hxor) << 4));
    }
    #pragma unroll
    for (int nf = 0; nf < 16; ++nf) {
      const int n = nf*16 + fr;
      bf16x8 w2f = *(const bf16x8*)&W2s[cur][n*32 + ((fg ^ ((n >> 1) & 3)) << 3)];
      acc2[0][nf] = __builtin_amdgcn_mfma_f32_16x16x32_bf16(hf2[0], w2f, acc2[0][nf], 0, 0, 0);
      acc2[1][nf] = __builtin_amdgcn_mfma_f32_16x16x32_bf16(hf2[1], w2f, acc2[1][nf], 0, 0, 0);
    }
  };

  stage(0, 0);
  stage(1, 1);
  for (int hb = 0; hb < 30; ++hb) {
    stage((hb + 2) & 3, hb + 2);
    asm volatile("s_waitcnt vmcnt(8)" ::: "memory");
    __builtin_amdgcn_s_barrier();
    __builtin_amdgcn_sched_barrier(0);
    compute_slice(hb, hb & 3);
  }
  asm volatile("s_waitcnt vmcnt(4)" ::: "memory");
  __builtin_amdgcn_s_barrier();
  __builtin_amdgcn_sched_barrier(0);
  compute_slice(30, 30 & 3);
  asm volatile("s_waitcnt vmcnt(0)" ::: "memory");
  __builtin_amdgcn_s_barrier();
  __builtin_amdgcn_sched_barrier(0);
  compute_slice(31, 31 & 3);

  #pragma unroll
  for (int g2 = 0; g2 < 2; ++g2) {
    const int rbase = row0 + g2*16 + fg*4;
    float s1[4] = {}, sq[4] = {};
    #pragma unroll
    for (int nf = 0; nf < 16; ++nf) {
      const int c = nf*16 + fr;
      const float b = b2[c];
      #pragma unroll
      for (int t = 0; t < 4; ++t) {
        float v = acc2[g2][nf][t] + b + bf2f(X[(size_t)(rbase + t) * 256 + c]);
        acc2[g2][nf][t] = v;
        s1[t] += v; sq[t] += v * v;
      }
    }
    #pragma unroll
    for (int d = 1; d < 16; d <<= 1) {
      #pragma unroll
      for (int t = 0; t < 4; ++t) {
        s1[t] += __shfl_xor(s1[t], d, 64);
        sq[t] += __shfl_xor(sq[t], d, 64);
      }
    }
    float mean[4], rstd[4];
    #pragma unroll
    for (int t = 0; t < 4; ++t) {
      mean[t] = s1[t] * (1.f/256.f);
      const float var = sq[t] * (1.f/256.f) - mean[t]*mean[t];
      rstd[t] = rsqrtf(var + 1e-5f);
    }
    #pragma unroll
    for (int nf = 0; nf < 16; ++nf) {
      const int c = nf*16 + fr;
      const float gc = g[c], bc = be[c];
      #pragma unroll
      for (int t = 0; t < 4; ++t) {
        const float y = (acc2[g2][nf][t] - mean[t]) * rstd[t] * gc + bc;
        if (OUT_F32) ((float*)Y)[(size_t)(rbase + t) * 256 + c] = y;
        else         ((u16*)Y)[(size_t)(rbase + t) * 256 + c] = f2bf(y);
      }
    }
  }
}

// ---------------------------------------------------------------------------
// MFMA windowed attention (unchanged).
// ---------------------------------------------------------------------------
__global__ __launch_bounds__(256) void attn_mfma(
    const u16* Q, int sq, const u16* __restrict__ K, int sk,
    const u16* __restrict__ Vt, u16* O, int so)
{
  __shared__ u16 P[4][32 * 40];
  const int tid = threadIdx.x, lane = tid & 63, w = tid >> 6;
  const int win = blockIdx.x * 4 + w;
  const size_t q0 = (size_t)win * 32;
  const int fr = lane & 15, fg = lane >> 4;
  u16* Pw = &P[w][0];
  const float scale = 0.17677669529663687f;

  for (int h = 0; h < 8; ++h) {
    const int co = h * 32;
    bf16x8 qa[2], kb[2];
    #pragma unroll
    for (int i = 0; i < 2; ++i)
      qa[i] = *(const bf16x8*)&Q[(q0 + i*16 + fr) * sq + co + fg*8];
    #pragma unroll
    for (int j = 0; j < 2; ++j)
      kb[j] = *(const bf16x8*)&K[(q0 + j*16 + fr) * sk + co + fg*8];
    f32x4 s[2][2] = {};
    #pragma unroll
    for (int i = 0; i < 2; ++i)
      #pragma unroll
      for (int j = 0; j < 2; ++j)
        s[i][j] = __builtin_amdgcn_mfma_f32_16x16x32_bf16(qa[i], kb[j], s[i][j], 0, 0, 0);

    float inv[2][4];
    #pragma unroll
    for (int i = 0; i < 2; ++i) {
      #pragma unroll
      for (int t = 0; t < 4; ++t) {
        float a0 = s[i][0][t] * scale, a1 = s[i][1][t] * scale;
        float mx = fmaxf(a0, a1);
        #pragma unroll
        for (int d = 1; d < 16; d <<= 1) mx = fmaxf(mx, __shfl_xor(mx, d, 64));
        const float p0 = __expf(a0 - mx), p1 = __expf(a1 - mx);
        float sm = p0 + p1;
        #pragma unroll
        for (int d = 1; d < 16; d <<= 1) sm += __shfl_xor(sm, d, 64);
        inv[i][t] = 1.f / sm;
        const int q = i*16 + fg*4 + t;
        Pw[q*40 + fr]      = f2bf(p0);
        Pw[q*40 + 16 + fr] = f2bf(p1);
      }
    }

    bf16x8 pa[2], vb[2];
    #pragma unroll
    for (int i = 0; i < 2; ++i)
      pa[i] = *(const bf16x8*)&Pw[(i*16 + fr)*40 + fg*8];
    #pragma unroll
    for (int j = 0; j < 2; ++j)
      vb[j] = *(const bf16x8*)&Vt[(size_t)win*8192 + (co + j*16 + fr)*32 + fg*8];
    f32x4 oacc[2][2] = {};
    #pragma unroll
    for (int i = 0; i < 2; ++i)
      #pragma unroll
      for (int j = 0; j < 2; ++j)
        oacc[i][j] = __builtin_amdgcn_mfma_f32_16x16x32_bf16(pa[i], vb[j], oacc[i][j], 0, 0, 0);

    #pragma unroll
    for (int i = 0; i < 2; ++i)
      #pragma unroll
      for (int j = 0; j < 2; ++j)
        #pragma unroll
        for (int t = 0; t < 4; ++t)
          O[(q0 + i*16 + fg*4 + t) * so + co + j*16 + fr] =
              f2bf(oacc[i][j][t] * inv[i][t]);
  }
}

// ---------------------------------------------------------------------------
// All weight prep in ONE launch (unchanged).
// ---------------------------------------------------------------------------
__global__ __launch_bounds__(256) void wprep_all(
    const float* __restrict__ Wq, const float* __restrict__ Wk,
    const float* __restrict__ Wv, const float* __restrict__ Wo,
    const float* __restrict__ W1, const float* __restrict__ W2,
    const float* __restrict__ bq, const float* __restrict__ bk,
    const float* __restrict__ bv,
    u16* __restrict__ WqkvT, u16* __restrict__ WoT,
    u16* __restrict__ W1T, u16* __restrict__ W2T, float* __restrict__ bqkv)
{
  const int b = blockIdx.x, t = threadIdx.x;
  if (b < 1024) {
    const int which = b >> 8, idx = ((b & 255) << 8) + t;
    const float* W = which == 0 ? Wq : which == 1 ? Wk : which == 2 ? Wv : Wo;
    u16* Wt = which == 3 ? WoT : WqkvT + which * 65536;
    const int k = idx >> 8, n = idx & 255;
    Wt[n * 256 + k] = f2bf(W[idx]);
  } else if (b < 2048) {
    const int idx = ((b - 1024) << 8) + t;
    const int k = idx >> 10, n = idx & 1023;
    W1T[n * 256 + k] = f2bf(W1[idx]);
  } else if (b < 3072) {
    const int idx = ((b - 2048) << 8) + t;
    const int k = idx >> 8, n = idx & 255;
    W2T[n * 1024 + k] = f2bf(W2[idx]);
  } else {
    const int i = ((b - 3072) << 8) + t;
    bqkv[i] = i < 256 ? bq[i] : (i < 512 ? bk[i - 256] : bv[i - 512]);
  }
}

// ---------------------------------------------------------------------------
extern "C" void kernel_launch(void* const* d_in, const int* in_sizes, int n_in,
                              void* d_out, int out_size, void* d_ws, size_t ws_size,
                              hipStream_t stream)
{
  const float* query  = (const float*)d_in[0];
  const float* keyval = (const float*)d_in[1];
  const float* Wq = (const float*)d_in[2];  const float* bq  = (const float*)d_in[3];
  const float* Wk = (const float*)d_in[4];  const float* bk  = (const float*)d_in[5];
  const float* Wv = (const float*)d_in[6];  const float* bv  = (const float*)d_in[7];
  const float* Wo = (const float*)d_in[8];  const float* bo  = (const float*)d_in[9];
  const float* g1 = (const float*)d_in[10]; const float* be1 = (const float*)d_in[11];
  const float* W1 = (const float*)d_in[12]; const float* bf1 = (const float*)d_in[13];
  const float* W2 = (const float*)d_in[14]; const float* bf2 = (const float*)d_in[15];
  const float* g2 = (const float*)d_in[16]; const float* be2 = (const float*)d_in[17];

  const int M = 131072;      // B*L token rows
  char* ws = (char*)d_ws;
  u16*  xcur = (u16*)ws;
  u16*  x1   = (u16*)(ws + (64ull  << 20));
  u16*  QKc  = (u16*)(ws + (256ull << 20));
  u16*  Vtc  = (u16*)(ws + (384ull << 20));
  u16*  WqkvT = (u16*)(ws + (448ull << 20));   // [768][256] = Wq|Wk|Wv rows
  u16*  WoT   = WqkvT + 196608;                // [256][256]
  u16*  W1T   = WoT   + 65536;                 // [1024][256]
  u16*  W2T   = W1T   + 262144;                // [256][1024]
  float* bqkv = (float*)(W2T + 262144);        // [768]
  float* bkv  = bqkv + 256;                    // [512] = bk|bv

  wprep_all<<<3075, 256, 0, stream>>>(Wq, Wk, Wv, Wo, W1, W2, bq, bk, bv,
                                      WqkvT, WoT, W1T, W2T, bqkv);

  // NOTE: jnp.roll(x, -16, axis=1) permutes whole windows; the encoder layer is
  // window-local and position-independent, so roll + layer + unroll == layer.
  // Both rolls are elided (bit-exact equivalence).

  // ---- layer 1: A inputs are raw fp32 (depth-2 piped staging) ----
  gemm_l1<<<6144, 256, 0, stream>>>(query, keyval, WqkvT, bq, bkv, QKc, Vtc);
  attn_mfma<<<1024, 256, 0, stream>>>(QKc, 512, QKc + 256, 512, Vtc, QKc, 512);
  gemm_oln<1><<<1024, 512, 0, stream>>>(
      QKc, 512, WoT, bo, query, g1, be1, x1, 256);        // residual = fp32 query
  ffn_fused<0><<<512, 512, 0, stream>>>(
      x1, W1T, bf1, W2T, bf2, g2, be2, xcur);

  // ---- layer 2: q = kv = xcur (bf16) ----
  gemm_bt<2><<<6144, 256, 0, stream>>>(
      xcur, 256, WqkvT, bqkv, QKc, 512, 0, Vtc, 512, 768, 256, 6);
  attn_mfma<<<1024, 256, 0, stream>>>(QKc, 512, QKc + 256, 512, Vtc, QKc, 512);
  gemm_oln<0><<<1024, 512, 0, stream>>>(
      QKc, 512, WoT, bo, xcur, g1, be1, x1, 256);         // residual = bf16 xcur
  ffn_fused<1><<<512, 512, 0, stream>>>(
      x1, W1T, bf1, W2T, bf2, g2, be2, d_out);
}

// Round 21
// 853.000 us; speedup vs baseline: 1.0986x; 1.0331x over previous
//
#include <hip/hip_runtime.h>
#include <cstdint>
#include <cstddef>

typedef unsigned short u16;
typedef __bf16 bf16x8 __attribute__((ext_vector_type(8)));
typedef float f32x4 __attribute__((ext_vector_type(4)));
typedef unsigned short u16x8 __attribute__((ext_vector_type(8)));
typedef unsigned short u16x4 __attribute__((ext_vector_type(4)));

__device__ __forceinline__ u16 f2bf(float f) {
  union { float f; unsigned u; } x; x.f = f;
  unsigned r = x.u + 0x7fffu + ((x.u >> 16) & 1u);   // RNE
  return (u16)(r >> 16);
}
__device__ __forceinline__ float bf2f(u16 u) {
  union { unsigned u; float f; } x; x.u = ((unsigned)u) << 16;
  return x.f;
}
// async global->LDS, 16B/lane; LDS dest = wave-uniform base + lane*16 (linear)
__device__ __forceinline__ void gload16(const void* g, void* l) {
  __builtin_amdgcn_global_load_lds(
      (const __attribute__((address_space(1))) unsigned int*)g,
      (__attribute__((address_space(3))) unsigned int*)l, 16, 0, 0);
}

// ---------------------------------------------------------------------------
// bf16 GEMM (layer 2): C = A[.][K](lda) @ Bt^T + bias. 128x128 tile, BK=32,
// 4 waves, 2-phase double-buffered, slot swizzle slot^(row&3) both sides.
// MODE 2: split route: col<vsplit natural into C0 (+coff);
//         col>=vsplit window-transposed into C2[win][c-vsplit][tok&31]
// ---------------------------------------------------------------------------
template<int MODE>
__global__ __launch_bounds__(256) void gemm_bt(
    const u16* __restrict__ Ab, int lda, const u16* __restrict__ Bt,
    const float* __restrict__ bias, u16* __restrict__ C0, int ldc, int coff,
    u16* __restrict__ C2, int vsplit, int N, int K, int gy)
{
  __shared__ u16 As[2 * 128 * 32];
  __shared__ u16 Bs[2 * 128 * 32];
  const int tid  = threadIdx.x;
  const int lane = tid & 63, w = tid >> 6;
  const int nwg = gridDim.x, o = blockIdx.x;
  const int lid = (o & 7) * (nwg >> 3) + (o >> 3);   // contiguous lid -> same XCD
  const int by = lid % gy, bx = lid / gy;
  const int row0 = bx * 128, col0 = by * 128;
  const int wr = (w >> 1) * 64, wc = (w & 1) * 64;
  const int fr = lane & 15, fg = lane >> 4;
  const int srow  = (w << 5) + (lane >> 2);
  const int sslot = (lane & 3) ^ ((lane >> 2) & 3);
  const int AB = 128 * 32;

  auto stageB = [&](int buf, int k0) {
    #pragma unroll
    for (int h = 0; h < 2; ++h)
      gload16((const char*)Bt + ((size_t)(col0 + srow + h*16) * K + k0) * 2 + sslot*16,
              &Bs[buf*AB + ((w << 5) + h*16) * 32]);
  };
  auto stageA16 = [&](int buf, int k0) {
    #pragma unroll
    for (int h = 0; h < 2; ++h)
      gload16((const char*)Ab + ((size_t)(row0 + srow + h*16) * lda + k0) * 2 + sslot*16,
              &As[buf*AB + ((w << 5) + h*16) * 32]);
  };

  f32x4 acc[4][4] = {};

  stageA16(0, 0); stageB(0, 0);
  __syncthreads();
  int cur = 0;
  for (int k0 = 0; k0 < K; k0 += 32) {
    if (k0 + 32 < K) { stageA16(cur ^ 1, k0 + 32); stageB(cur ^ 1, k0 + 32); }
    bf16x8 af[4], bf[4];
    #pragma unroll
    for (int i = 0; i < 4; ++i) {
      const int r = wr + i*16 + fr;
      af[i] = *(const bf16x8*)&As[cur*AB + r*32 + ((fg ^ (fr & 3)) << 3)];
    }
    #pragma unroll
    for (int j = 0; j < 4; ++j) {
      const int r = wc + j*16 + fr;
      bf[j] = *(const bf16x8*)&Bs[cur*AB + r*32 + ((fg ^ (fr & 3)) << 3)];
    }
    #pragma unroll
    for (int i = 0; i < 4; ++i)
      #pragma unroll
      for (int j = 0; j < 4; ++j)
        acc[i][j] = __builtin_amdgcn_mfma_f32_16x16x32_bf16(af[i], bf[j], acc[i][j], 0, 0, 0);
    __syncthreads();
    cur ^= 1;
  }

  const int vpart = (MODE == 2 && col0 >= vsplit);
  #pragma unroll
  for (int j = 0; j < 4; ++j) {
    const int c  = col0 + wc + j*16 + fr;
    const float bv = bias[c];
    #pragma unroll
    for (int i = 0; i < 4; ++i) {
      if (vpart) {
        const int cv = c - vsplit;
        const int rb = row0 + wr + i*16 + fg*4;
        u16x4 vv;
        #pragma unroll
        for (int t = 0; t < 4; ++t) vv[t] = f2bf(acc[i][j][t] + bv);
        *(u16x4*)&C2[((size_t)(rb >> 5) * 256 + cv) * 32 + (rb & 31)] = vv;
      } else {
        #pragma unroll
        for (int t = 0; t < 4; ++t) {
          const int r = row0 + wr + i*16 + fg*4 + t;
          C0[(size_t)r * ldc + coff + c] = f2bf(acc[i][j][t] + bv);
        }
      }
    }
  }
}

// ---------------------------------------------------------------------------
// Layer-1 projections, oln-geometry: 512 threads, 128 rows x 256 cols per
// block (8 waves as 2 row x 4 col of 64x64). Three 1024-block segments:
// seg 0 = Q (query -> QKc cols 0..255), seg 1 = K (keyval -> QKc cols
// 256..511), seg 2 = V (keyval -> Vtc window-transposed). Full 256-col tile
// per block => A fp32 converted ONCE per 256 output cols (8 f2bf/thread per
// K-step), 128 MFMA per barrier. T14 fp32-A split staging (load before
// compute, convert+swizzled ds_write after), verified slot involution
// LDS[r][s]=global[r][s^(r&3)] on both A and B sides. BK=32, 2-phase.
// ---------------------------------------------------------------------------
__global__ __launch_bounds__(512) void gemm_l1(
    const float* __restrict__ query, const float* __restrict__ keyval,
    const u16* __restrict__ WqkvT, const float* __restrict__ bqkv,
    u16* __restrict__ QKc, u16* __restrict__ Vtc)
{
  __shared__ u16 As[2][128 * 32];    // 8 KB x2
  __shared__ u16 Bs[2][256 * 32];    // 16 KB x2
  const int tid = threadIdx.x, lane = tid & 63, w = tid >> 6;
  const int o = blockIdx.x;
  const int seg = o >> 10, ob = o & 1023;
  const int lid = (ob & 7) * 128 + (ob >> 3);    // XCD chunk within segment
  const int row0 = lid * 128;
  const float* Af = (seg == 0) ? query : keyval;
  const u16* Bt = WqkvT + seg * 65536;           // [256][256] slice
  const float* bias = bqkv + seg * 256;
  const int wr = (w >> 2) * 64, wc = (w & 3) * 64;
  const int fr = lane & 15, fg = lane >> 4;
  const int sr = lane >> 2;
  const int sslot = (lane & 3) ^ ((lane >> 2) & 3);
  const int arr = tid >> 2, asl = tid & 3;       // fp32-A slot: 512 = 128x4

  auto stageB = [&](int buf, int k0) {
    #pragma unroll
    for (int h = 0; h < 2; ++h)
      gload16((const char*)Bt + ((size_t)((w << 5) + h*16 + sr) * 256 + k0) * 2 + sslot*16,
              &Bs[buf][((w << 5) + h*16) * 32]);
  };
  f32x4 pre0, pre1;
  auto loadA32 = [&](int k0) {
    const float* src = &Af[(size_t)(row0 + arr) * 256 + k0 + asl*8];
    pre0 = *(const f32x4*)src;
    pre1 = *(const f32x4*)(src + 4);
  };
  auto writeA32 = [&](int buf) {
    u16x8 ov = { f2bf(pre0[0]), f2bf(pre0[1]), f2bf(pre0[2]), f2bf(pre0[3]),
                 f2bf(pre1[0]), f2bf(pre1[1]), f2bf(pre1[2]), f2bf(pre1[3]) };
    *(u16x8*)&As[buf][arr*32 + ((asl ^ (arr & 3)) << 3)] = ov;
  };

  f32x4 acc[4][4] = {};

  loadA32(0); stageB(0, 0); writeA32(0);
  __syncthreads();                  // prologue drain (vm + lgkm)
  int cur = 0;
  for (int k0 = 0; k0 < 256; k0 += 32) {
    const int has_next = (k0 + 32 < 256);
    if (has_next) {                 // issue next-tile loads before compute
      loadA32(k0 + 32);
      stageB(cur ^ 1, k0 + 32);
    }
    bf16x8 af[4], bf[4];
    #pragma unroll
    for (int i = 0; i < 4; ++i) {
      const int r = wr + i*16 + fr;
      af[i] = *(const bf16x8*)&As[cur][r*32 + ((fg ^ (fr & 3)) << 3)];
    }
    #pragma unroll
    for (int j = 0; j < 4; ++j) {
      const int r = wc + j*16 + fr;
      bf[j] = *(const bf16x8*)&Bs[cur][r*32 + ((fg ^ (fr & 3)) << 3)];
    }
    #pragma unroll
    for (int i = 0; i < 4; ++i)
      #pragma unroll
      for (int j = 0; j < 4; ++j)
        acc[i][j] = __builtin_amdgcn_mfma_f32_16x16x32_bf16(af[i], bf[j], acc[i][j], 0, 0, 0);
    if (has_next) writeA32(cur ^ 1);   // T14: write-late
    __syncthreads();                // all reads done + next stage drained
    cur ^= 1;
  }

  // epilogue: D[row=fg*4+t][col=fr] per 16x16 fragment (m89-verified mapping)
  if (seg == 2) {                   // V -> window-transposed Vt
    #pragma unroll
    for (int j = 0; j < 4; ++j) {
      const int c = wc + j*16 + fr;
      const float bv = bias[c];
      #pragma unroll
      for (int i = 0; i < 4; ++i) {
        const int rb = row0 + wr + i*16 + fg*4;   // 4 consecutive tokens
        u16x4 vv;
        #pragma unroll
        for (int t = 0; t < 4; ++t) vv[t] = f2bf(acc[i][j][t] + bv);
        *(u16x4*)&Vtc[((size_t)(rb >> 5) * 256 + c) * 32 + (rb & 31)] = vv;
      }
    }
  } else {                          // Q / K -> natural into QKc
    const int coff = seg * 256;
    #pragma unroll
    for (int j = 0; j < 4; ++j) {
      const int c = wc + j*16 + fr;
      const float bv = bias[c];
      #pragma unroll
      for (int i = 0; i < 4; ++i) {
        #pragma unroll
        for (int t = 0; t < 4; ++t) {
          const int r = row0 + wr + i*16 + fg*4 + t;
          QKc[(size_t)r * 512 + coff + c] = f2bf(acc[i][j][t] + bv);
        }
      }
    }
  }
}

// ---------------------------------------------------------------------------
// O-proj + bias + residual + LayerNorm fused (full-row tile).
// 128 rows x 256 cols per block, 8 waves (2 row x 4 col of 64x64), BK=32.
// RES_F32: residual read as fp32 (layer 1: raw query) or bf16 (layer 2).
// ---------------------------------------------------------------------------
template<int RES_F32>
__global__ __launch_bounds__(512) void gemm_oln(
    const u16* __restrict__ Ap, int lda, const u16* __restrict__ Bt,
    const float* __restrict__ bias, const void* __restrict__ Res,
    const float* __restrict__ g, const float* __restrict__ be,
    u16* __restrict__ Y, int K)
{
  __shared__ u16 As[2][128 * 32];
  __shared__ u16 Bs[2][256 * 32];
  __shared__ float2 red[128][4];
  __shared__ float2 stats[128];
  const int tid  = threadIdx.x;
  const int lane = tid & 63, w = tid >> 6;
  const int nwg = gridDim.x, o = blockIdx.x;
  const int lid = (o & 7) * (nwg >> 3) + (o >> 3);
  const int row0 = lid * 128;
  const int wr = (w >> 2) * 64, wc = (w & 3) * 64;
  const int fr = lane & 15, fg = lane >> 4;
  const int sr   = lane >> 2;
  const int sslot = (lane & 3) ^ ((lane >> 2) & 3);

  auto stage = [&](int buf, int k0) {
    gload16((const char*)Ap + ((size_t)(row0 + (w << 4) + sr) * lda + k0) * 2 + sslot*16,
            &As[buf][((w << 4)) * 32]);
    #pragma unroll
    for (int h = 0; h < 2; ++h)
      gload16((const char*)Bt + ((size_t)((w << 5) + h*16 + sr) * K + k0) * 2 + sslot*16,
              &Bs[buf][((w << 5) + h*16) * 32]);
  };

  f32x4 acc[4][4] = {};

  stage(0, 0);
  __syncthreads();
  int cur = 0;
  for (int k0 = 0; k0 < K; k0 += 32) {
    if (k0 + 32 < K) stage(cur ^ 1, k0 + 32);
    bf16x8 af[4], bf[4];
    #pragma unroll
    for (int i = 0; i < 4; ++i) {
      const int r = wr + i*16 + fr;
      af[i] = *(const bf16x8*)&As[cur][r*32 + ((fg ^ (fr & 3)) << 3)];
    }
    #pragma unroll
    for (int j = 0; j < 4; ++j) {
      const int r = wc + j*16 + fr;
      bf[j] = *(const bf16x8*)&Bs[cur][r*32 + ((fg ^ (fr & 3)) << 3)];
    }
    #pragma unroll
    for (int i = 0; i < 4; ++i)
      #pragma unroll
      for (int j = 0; j < 4; ++j)
        acc[i][j] = __builtin_amdgcn_mfma_f32_16x16x32_bf16(af[i], bf[j], acc[i][j], 0, 0, 0);
    __syncthreads();
    cur ^= 1;
  }

  float ps[4][4] = {}, pq[4][4] = {};
  #pragma unroll
  for (int j = 0; j < 4; ++j) {
    const int c = wc + j*16 + fr;
    const float bv = bias[c];
    #pragma unroll
    for (int i = 0; i < 4; ++i) {
      #pragma unroll
      for (int t = 0; t < 4; ++t) {
        const int r = row0 + wr + i*16 + fg*4 + t;
        const float rv = RES_F32 ? ((const float*)Res)[(size_t)r * 256 + c]
                                 : bf2f(((const u16*)Res)[(size_t)r * 256 + c]);
        float v = acc[i][j][t] + bv + rv;
        acc[i][j][t] = v;
        ps[i][t] += v;
        pq[i][t] += v * v;
      }
    }
  }
  #pragma unroll
  for (int d = 1; d < 16; d <<= 1) {
    #pragma unroll
    for (int i = 0; i < 4; ++i)
      #pragma unroll
      for (int t = 0; t < 4; ++t) {
        ps[i][t] += __shfl_xor(ps[i][t], d, 64);
        pq[i][t] += __shfl_xor(pq[i][t], d, 64);
      }
  }
  if (fr == 0) {
    #pragma unroll
    for (int i = 0; i < 4; ++i)
      #pragma unroll
      for (int t = 0; t < 4; ++t)
        red[wr + i*16 + fg*4 + t][w & 3] = make_float2(ps[i][t], pq[i][t]);
  }
  __syncthreads();
  if (tid < 128) {
    float S = 0.f, Q = 0.f;
    #pragma unroll
    for (int ww = 0; ww < 4; ++ww) { float2 p = red[tid][ww]; S += p.x; Q += p.y; }
    const float m = S * (1.f/256.f);
    const float var = Q * (1.f/256.f) - m*m;
    stats[tid] = make_float2(m, rsqrtf(var + 1e-5f));
  }
  __syncthreads();
  #pragma unroll
  for (int i = 0; i < 4; ++i) {
    #pragma unroll
    for (int t = 0; t < 4; ++t) {
      const int rl = wr + i*16 + fg*4 + t;
      const float2 st = stats[rl];
      const size_t r = row0 + rl;
      #pragma unroll
      for (int j = 0; j < 4; ++j) {
        const int c = wc + j*16 + fr;
        Y[r * 256 + c] = f2bf((acc[i][j][t] - st.x) * st.y * g[c] + be[c]);
      }
    }
  }
}

// ---------------------------------------------------------------------------
// Fused FFN v4: Y = LayerNorm( X + relu(X@W1 + bf1)@W2 + bf2 ; g,be ).
// K32 GEMM2 via wave-private LDS H-bounce + T4 counted-vmcnt pipeline.
// ---------------------------------------------------------------------------
template<int OUT_F32>
__global__ __launch_bounds__(512, 2) void ffn_fused(
    const u16* __restrict__ X, const u16* __restrict__ W1T,
    const float* __restrict__ b1, const u16* __restrict__ W2T,
    const float* __restrict__ b2, const float* __restrict__ g,
    const float* __restrict__ be, void* __restrict__ Y)
{
  __shared__ u16 W1s[4][32 * 256];
  __shared__ u16 W2s[4][256 * 32];
  __shared__ u16 Hs[8][32 * 32];
  __shared__ float b1s[1024];
  const int tid = threadIdx.x, lane = tid & 63, w = tid >> 6;
  const int fr = lane & 15, fg = lane >> 4;
  const int row0 = blockIdx.x * 256 + w * 32;
  u16* Hw = &Hs[w][0];
  const int hxor = (fr >> 1) & 3;

  auto stage = [&](int buf, int hb) {
    #pragma unroll
    for (int h = 0; h < 2; ++h) {
      const int r = w*4 + h*2 + (lane >> 5);
      const int sl = (lane & 31) ^ (r & 7);
      gload16((const char*)W1T + ((size_t)((hb << 5) + r) * 256 + sl*8) * 2,
              &W1s[buf][(w*4 + h*2) * 256]);
    }
    #pragma unroll
    for (int h = 0; h < 2; ++h) {
      const int r = w*32 + h*16 + (lane >> 2);
      const int sl = (lane & 3) ^ ((r >> 1) & 3);
      gload16((const char*)W2T + ((size_t)r * 1024 + (hb << 5) + sl*8) * 2,
              &W2s[buf][(w*32 + h*16) * 32]);
    }
  };

  if (tid < 256) {
    f32x4 bv = *(const f32x4*)&b1[tid * 4];
    *(f32x4*)&b1s[tid * 4] = bv;
  }
  bf16x8 af[2][8];
  #pragma unroll
  for (int g2 = 0; g2 < 2; ++g2)
    #pragma unroll
    for (int kf = 0; kf < 8; ++kf)
      af[g2][kf] = *(const bf16x8*)&X[(size_t)(row0 + g2*16 + fr) * 256 + kf*32 + fg*8];
  asm volatile("s_waitcnt vmcnt(0)" ::: "memory");

  f32x4 acc2[2][16] = {};

  auto compute_slice = [&](int hb, int cur) {
    f32x4 acc1[2][2] = {};
    #pragma unroll
    for (int kf = 0; kf < 8; ++kf) {
      #pragma unroll
      for (int hf = 0; hf < 2; ++hf) {
        const int n = hf*16 + fr;
        bf16x8 w1f = *(const bf16x8*)&W1s[cur][n*256 + ((((kf << 2) | fg) ^ (n & 7)) << 3)];
        acc1[hf][0] = __builtin_amdgcn_mfma_f32_16x16x32_bf16(w1f, af[0][kf], acc1[hf][0], 0, 0, 0);
        acc1[hf][1] = __builtin_amdgcn_mfma_f32_16x16x32_bf16(w1f, af[1][kf], acc1[hf][1], 0, 0, 0);
      }
    }
    #pragma unroll
    for (int g2 = 0; g2 < 2; ++g2) {
      #pragma unroll
      for (int hf = 0; hf < 2; ++hf) {
        const int h0 = hf*16 + fg*4;
        f32x4 b4 = *(const f32x4*)&b1s[(hb << 5) + h0];
        u16x4 hv;
        #pragma unroll
        for (int t = 0; t < 4; ++t) {
          float v = acc1[hf][g2][t] + b4[t];
          hv[t] = f2bf(v > 0.f ? v : 0.f);
        }
        const int tok = g2*16 + fr;
        *(u16x4*)((char*)Hw + tok*64 + ((((hf << 1) | (fg >> 1)) ^ hxor) << 4)
                                     + ((fg & 1) << 3)) = hv;
      }
    }
    asm volatile("s_waitcnt lgkmcnt(0)" ::: "memory");
    __builtin_amdgcn_sched_barrier(0);

    bf16x8 hf2[2];
    #pragma unroll
    for (int g2 = 0; g2 < 2; ++g2) {
      const int tok = g2*16 + fr;
      hf2[g2] = *(const bf16x8*)((char*)Hw + tok*64 + ((fg ^ hxor) << 4));
    }
    #pragma unroll
    for (int nf = 0; nf < 16; ++nf) {
      const int n = nf*16 + fr;
      bf16x8 w2f = *(const bf16x8*)&W2s[cur][n*32 + ((fg ^ ((n >> 1) & 3)) << 3)];
      acc2[0][nf] = __builtin_amdgcn_mfma_f32_16x16x32_bf16(hf2[0], w2f, acc2[0][nf], 0, 0, 0);
      acc2[1][nf] = __builtin_amdgcn_mfma_f32_16x16x32_bf16(hf2[1], w2f, acc2[1][nf], 0, 0, 0);
    }
  };

  stage(0, 0);
  stage(1, 1);
  for (int hb = 0; hb < 30; ++hb) {
    stage((hb + 2) & 3, hb + 2);
    asm volatile("s_waitcnt vmcnt(8)" ::: "memory");
    __builtin_amdgcn_s_barrier();
    __builtin_amdgcn_sched_barrier(0);
    compute_slice(hb, hb & 3);
  }
  asm volatile("s_waitcnt vmcnt(4)" ::: "memory");
  __builtin_amdgcn_s_barrier();
  __builtin_amdgcn_sched_barrier(0);
  compute_slice(30, 30 & 3);
  asm volatile("s_waitcnt vmcnt(0)" ::: "memory");
  __builtin_amdgcn_s_barrier();
  __builtin_amdgcn_sched_barrier(0);
  compute_slice(31, 31 & 3);

  #pragma unroll
  for (int g2 = 0; g2 < 2; ++g2) {
    const int rbase = row0 + g2*16 + fg*4;
    float s1[4] = {}, sq[4] = {};
    #pragma unroll
    for (int nf = 0; nf < 16; ++nf) {
      const int c = nf*16 + fr;
      const float b = b2[c];
      #pragma unroll
      for (int t = 0; t < 4; ++t) {
        float v = acc2[g2][nf][t] + b + bf2f(X[(size_t)(rbase + t) * 256 + c]);
        acc2[g2][nf][t] = v;
        s1[t] += v; sq[t] += v * v;
      }
    }
    #pragma unroll
    for (int d = 1; d < 16; d <<= 1) {
      #pragma unroll
      for (int t = 0; t < 4; ++t) {
        s1[t] += __shfl_xor(s1[t], d, 64);
        sq[t] += __shfl_xor(sq[t], d, 64);
      }
    }
    float mean[4], rstd[4];
    #pragma unroll
    for (int t = 0; t < 4; ++t) {
      mean[t] = s1[t] * (1.f/256.f);
      const float var = sq[t] * (1.f/256.f) - mean[t]*mean[t];
      rstd[t] = rsqrtf(var + 1e-5f);
    }
    #pragma unroll
    for (int nf = 0; nf < 16; ++nf) {
      const int c = nf*16 + fr;
      const float gc = g[c], bc = be[c];
      #pragma unroll
      for (int t = 0; t < 4; ++t) {
        const float y = (acc2[g2][nf][t] - mean[t]) * rstd[t] * gc + bc;
        if (OUT_F32) ((float*)Y)[(size_t)(rbase + t) * 256 + c] = y;
        else         ((u16*)Y)[(size_t)(rbase + t) * 256 + c] = f2bf(y);
      }
    }
  }
}

// ---------------------------------------------------------------------------
// MFMA windowed attention (unchanged).
// ---------------------------------------------------------------------------
__global__ __launch_bounds__(256) void attn_mfma(
    const u16* Q, int sq, const u16* __restrict__ K, int sk,
    const u16* __restrict__ Vt, u16* O, int so)
{
  __shared__ u16 P[4][32 * 40];
  const int tid = threadIdx.x, lane = tid & 63, w = tid >> 6;
  const int win = blockIdx.x * 4 + w;
  const size_t q0 = (size_t)win * 32;
  const int fr = lane & 15, fg = lane >> 4;
  u16* Pw = &P[w][0];
  const float scale = 0.17677669529663687f;

  for (int h = 0; h < 8; ++h) {
    const int co = h * 32;
    bf16x8 qa[2], kb[2];
    #pragma unroll
    for (int i = 0; i < 2; ++i)
      qa[i] = *(const bf16x8*)&Q[(q0 + i*16 + fr) * sq + co + fg*8];
    #pragma unroll
    for (int j = 0; j < 2; ++j)
      kb[j] = *(const bf16x8*)&K[(q0 + j*16 + fr) * sk + co + fg*8];
    f32x4 s[2][2] = {};
    #pragma unroll
    for (int i = 0; i < 2; ++i)
      #pragma unroll
      for (int j = 0; j < 2; ++j)
        s[i][j] = __builtin_amdgcn_mfma_f32_16x16x32_bf16(qa[i], kb[j], s[i][j], 0, 0, 0);

    float inv[2][4];
    #pragma unroll
    for (int i = 0; i < 2; ++i) {
      #pragma unroll
      for (int t = 0; t < 4; ++t) {
        float a0 = s[i][0][t] * scale, a1 = s[i][1][t] * scale;
        float mx = fmaxf(a0, a1);
        #pragma unroll
        for (int d = 1; d < 16; d <<= 1) mx = fmaxf(mx, __shfl_xor(mx, d, 64));
        const float p0 = __expf(a0 - mx), p1 = __expf(a1 - mx);
        float sm = p0 + p1;
        #pragma unroll
        for (int d = 1; d < 16; d <<= 1) sm += __shfl_xor(sm, d, 64);
        inv[i][t] = 1.f / sm;
        const int q = i*16 + fg*4 + t;
        Pw[q*40 + fr]      = f2bf(p0);
        Pw[q*40 + 16 + fr] = f2bf(p1);
      }
    }

    bf16x8 pa[2], vb[2];
    #pragma unroll
    for (int i = 0; i < 2; ++i)
      pa[i] = *(const bf16x8*)&Pw[(i*16 + fr)*40 + fg*8];
    #pragma unroll
    for (int j = 0; j < 2; ++j)
      vb[j] = *(const bf16x8*)&Vt[(size_t)win*8192 + (co + j*16 + fr)*32 + fg*8];
    f32x4 oacc[2][2] = {};
    #pragma unroll
    for (int i = 0; i < 2; ++i)
      #pragma unroll
      for (int j = 0; j < 2; ++j)
        oacc[i][j] = __builtin_amdgcn_mfma_f32_16x16x32_bf16(pa[i], vb[j], oacc[i][j], 0, 0, 0);

    #pragma unroll
    for (int i = 0; i < 2; ++i)
      #pragma unroll
      for (int j = 0; j < 2; ++j)
        #pragma unroll
        for (int t = 0; t < 4; ++t)
          O[(q0 + i*16 + fg*4 + t) * so + co + j*16 + fr] =
              f2bf(oacc[i][j][t] * inv[i][t]);
  }
}

// ---------------------------------------------------------------------------
// All weight prep in ONE launch (unchanged).
// ---------------------------------------------------------------------------
__global__ __launch_bounds__(256) void wprep_all(
    const float* __restrict__ Wq, const float* __restrict__ Wk,
    const float* __restrict__ Wv, const float* __restrict__ Wo,
    const float* __restrict__ W1, const float* __restrict__ W2,
    const float* __restrict__ bq, const float* __restrict__ bk,
    const float* __restrict__ bv,
    u16* __restrict__ WqkvT, u16* __restrict__ WoT,
    u16* __restrict__ W1T, u16* __restrict__ W2T, float* __restrict__ bqkv)
{
  const int b = blockIdx.x, t = threadIdx.x;
  if (b < 1024) {
    const int which = b >> 8, idx = ((b & 255) << 8) + t;
    const float* W = which == 0 ? Wq : which == 1 ? Wk : which == 2 ? Wv : Wo;
    u16* Wt = which == 3 ? WoT : WqkvT + which * 65536;
    const int k = idx >> 8, n = idx & 255;
    Wt[n * 256 + k] = f2bf(W[idx]);
  } else if (b < 2048) {
    const int idx = ((b - 1024) << 8) + t;
    const int k = idx >> 10, n = idx & 1023;
    W1T[n * 256 + k] = f2bf(W1[idx]);
  } else if (b < 3072) {
    const int idx = ((b - 2048) << 8) + t;
    const int k = idx >> 8, n = idx & 255;
    W2T[n * 1024 + k] = f2bf(W2[idx]);
  } else {
    const int i = ((b - 3072) << 8) + t;
    bqkv[i] = i < 256 ? bq[i] : (i < 512 ? bk[i - 256] : bv[i - 512]);
  }
}

// ---------------------------------------------------------------------------
extern "C" void kernel_launch(void* const* d_in, const int* in_sizes, int n_in,
                              void* d_out, int out_size, void* d_ws, size_t ws_size,
                              hipStream_t stream)
{
  const float* query  = (const float*)d_in[0];
  const float* keyval = (const float*)d_in[1];
  const float* Wq = (const float*)d_in[2];  const float* bq  = (const float*)d_in[3];
  const float* Wk = (const float*)d_in[4];  const float* bk  = (const float*)d_in[5];
  const float* Wv = (const float*)d_in[6];  const float* bv  = (const float*)d_in[7];
  const float* Wo = (const float*)d_in[8];  const float* bo  = (const float*)d_in[9];
  const float* g1 = (const float*)d_in[10]; const float* be1 = (const float*)d_in[11];
  const float* W1 = (const float*)d_in[12]; const float* bf1 = (const float*)d_in[13];
  const float* W2 = (const float*)d_in[14]; const float* bf2 = (const float*)d_in[15];
  const float* g2 = (const float*)d_in[16]; const float* be2 = (const float*)d_in[17];

  const int M = 131072;      // B*L token rows
  char* ws = (char*)d_ws;
  u16*  xcur = (u16*)ws;
  u16*  x1   = (u16*)(ws + (64ull  << 20));
  u16*  QKc  = (u16*)(ws + (256ull << 20));
  u16*  Vtc  = (u16*)(ws + (384ull << 20));
  u16*  WqkvT = (u16*)(ws + (448ull << 20));   // [768][256] = Wq|Wk|Wv rows
  u16*  WoT   = WqkvT + 196608;                // [256][256]
  u16*  W1T   = WoT   + 65536;                 // [1024][256]
  u16*  W2T   = W1T   + 262144;                // [256][1024]
  float* bqkv = (float*)(W2T + 262144);        // [768]

  wprep_all<<<3075, 256, 0, stream>>>(Wq, Wk, Wv, Wo, W1, W2, bq, bk, bv,
                                      WqkvT, WoT, W1T, W2T, bqkv);

  // NOTE: jnp.roll(x, -16, axis=1) permutes whole windows; the encoder layer is
  // window-local and position-independent, so roll + layer + unroll == layer.
  // Both rolls are elided (bit-exact equivalence).

  // ---- layer 1: A inputs are raw fp32 (converted during GEMM staging) ----
  gemm_l1<<<3072, 512, 0, stream>>>(query, keyval, WqkvT, bqkv, QKc, Vtc);
  attn_mfma<<<1024, 256, 0, stream>>>(QKc, 512, QKc + 256, 512, Vtc, QKc, 512);
  gemm_oln<1><<<1024, 512, 0, stream>>>(
      QKc, 512, WoT, bo, query, g1, be1, x1, 256);        // residual = fp32 query
  ffn_fused<0><<<512, 512, 0, stream>>>(
      x1, W1T, bf1, W2T, bf2, g2, be2, xcur);

  // ---- layer 2: q = kv = xcur (bf16) ----
  gemm_bt<2><<<6144, 256, 0, stream>>>(
      xcur, 256, WqkvT, bqkv, QKc, 512, 0, Vtc, 512, 768, 256, 6);
  attn_mfma<<<1024, 256, 0, stream>>>(QKc, 512, QKc + 256, 512, Vtc, QKc, 512);
  gemm_oln<0><<<1024, 512, 0, stream>>>(
      QKc, 512, WoT, bo, xcur, g1, be1, x1, 256);         // residual = bf16 xcur
  ffn_fused<1><<<512, 512, 0, stream>>>(
      x1, W1T, bf1, W2T, bf2, g2, be2, d_out);
}